// Round 6
// baseline (678.109 us; speedup 1.0000x reference)
//
#include <hip/hip_runtime.h>
#include <math.h>

// ---------------- constants ----------------
constexpr int BB   = 64;
constexpr int NPB  = 1024;            // nodes per batch graph (N1+N2)
constexpr int NN   = BB * NPB;        // 65536 total nodes
constexpr int EALL = 1048576;         // total edges (both communities)
constexpr int EC   = 524288;          // edges per community
constexpr int EPG  = 8192;            // edges per (batch,community) group == N1*DEG
constexpr int KTOP = 256;             // K1 == K2
constexpr int NP   = BB * KTOP;       // 16384 pooled nodes per community
constexpr int NP2  = 2 * NP;          // 32768 pooled nodes total

// physical quad swizzle for Ws: bijective on 0..31; even/odd read sequences land 2-way (free)
__device__ __forceinline__ int pq(int q) { return q ^ (q >> 3); }

// ---------------- full-graph CSR build: per-group LDS counting sort ----------------
__global__ __launch_bounds__(256) void k_build_csr(const int* __restrict__ src_all,
                                                   const int* __restrict__ dst_all,
                                                   int* __restrict__ rowstart,
                                                   int* __restrict__ csrc,
                                                   float* __restrict__ dis) {
    __shared__ int cnt[512];
    __shared__ int rs[512];
    __shared__ int wsum[4];
    __shared__ int stage[EPG];
    const int g = blockIdx.x;
    const int b = g >> 1, c = g & 1;
    const int ebase  = c * EC + b * EPG;
    const int region = g * EPG;
    const int nbase  = g * 512;
    const int t = threadIdx.x;
    const int lane = t & 63, w = t >> 6;

    cnt[t] = 0; cnt[t + 256] = 0;
    __syncthreads();
    for (int i = 0; i < 32; i++) {
        int d = dst_all[ebase + t + 256 * i] & 511;
        atomicAdd(&cnt[d], 1);
    }
    __syncthreads();
    int v0 = cnt[2 * t], v1 = cnt[2 * t + 1];
    int p = v0 + v1;
    int incl = p;
    for (int off = 1; off < 64; off <<= 1) {
        int u = __shfl_up(incl, off);
        if (lane >= off) incl += u;
    }
    if (lane == 63) wsum[w] = incl;
    __syncthreads();
    int base = 0;
    for (int i = 0; i < w; i++) base += wsum[i];
    int excl = base + incl - p;
    rs[2 * t] = excl;
    rs[2 * t + 1] = excl + v0;
    rowstart[nbase + 2 * t]     = region + excl;
    rowstart[nbase + 2 * t + 1] = region + excl + v0;
    dis[nbase + 2 * t]     = 1.0f / sqrtf((float)v0 + 1.0f);
    dis[nbase + 2 * t + 1] = 1.0f / sqrtf((float)v1 + 1.0f);
    if (g == 127 && t == 0) rowstart[NN] = EALL;
    __syncthreads();
    for (int i = 0; i < 32; i++) {
        int e = ebase + t + 256 * i;
        int d = dst_all[e] & 511;
        int pp = atomicAdd(&rs[d], 1);
        stage[pp] = src_all[e];
    }
    __syncthreads();
    for (int i = 0; i < 32; i++)
        csrc[region + t + 256 * i] = stage[t + 256 * i];
}

// ---------------- pooled CSR build ----------------
__global__ __launch_bounds__(256) void k_build_csr_pooled(const int* __restrict__ s1,
                                                          const int* __restrict__ d1,
                                                          const int* __restrict__ s2,
                                                          const int* __restrict__ d2,
                                                          const int* __restrict__ nmap,
                                                          int* __restrict__ rowstart,
                                                          int* __restrict__ cntp,
                                                          int* __restrict__ csre,
                                                          float* __restrict__ disp) {
    __shared__ int cnt[256];
    __shared__ int rs[256];
    __shared__ int wsum[4];
    __shared__ int stage[EPG];
    const int g = blockIdx.x;
    const int c = g >> 6, b = g & 63;
    const int* ss = c ? s2 : s1;
    const int* dd = c ? d2 : d1;
    const int* nm = nmap + c * 32768;
    const int ebase  = b * EPG;
    const int region = g * EPG;
    const int nbase  = g * 256;
    const int t = threadIdx.x;
    const int lane = t & 63, w = t >> 6;

    cnt[t] = 0;
    __syncthreads();
    for (int i = 0; i < 32; i++) {
        int e = ebase + t + 256 * i;
        int r = nm[ss[e]], cc = nm[dd[e]];
        if (r >= 0 && cc >= 0) atomicAdd(&cnt[cc & 255], 1);
    }
    __syncthreads();
    int v = cnt[t];
    int incl = v;
    for (int off = 1; off < 64; off <<= 1) {
        int u = __shfl_up(incl, off);
        if (lane >= off) incl += u;
    }
    if (lane == 63) wsum[w] = incl;
    __syncthreads();
    int base = 0;
    for (int i = 0; i < w; i++) base += wsum[i];
    int excl = base + incl - v;
    rs[t] = excl;
    rowstart[nbase + t] = region + excl;
    cntp[nbase + t] = v;
    disp[nbase + t] = 1.0f / sqrtf((float)v + 1.0f);
    __syncthreads();
    for (int i = 0; i < 32; i++) {
        int e = ebase + t + 256 * i;
        int r = nm[ss[e]], cc = nm[dd[e]];
        if (r >= 0 && cc >= 0) {
            int pp = atomicAdd(&rs[cc & 255], 1);
            stage[pp] = r;
        }
    }
    __syncthreads();
    for (int i = 0; i < 32; i++)
        csre[region + t + 256 * i] = stage[t + 256 * i];
}

// ---------------- GEMM: C[M x 128] = A[M x KDIM] @ W[KDIM x 128], row-scaled ----------------
// single-buffered, reg-prefetch; As stride 132 (2-way writes, aligned b128 reads);
// Ws quad-swizzled pq (2-way reads/writes).
template <int KDIM>
__global__ __launch_bounds__(256) void k_gemm_tile(const float* __restrict__ A, int lda,
                                                   const float* __restrict__ W,
                                                   const float* __restrict__ rowscale,
                                                   float* __restrict__ C, int M) {
    __shared__ float As[32][132];
    __shared__ float Ws[32 * 128];
    const int tid  = threadIdx.x;
    const int c0 = (tid & 15) * 8;
    const int r0 = (tid >> 4) * 8;
    const int row0 = blockIdx.x * 128;
    const int arow = tid >> 1;
    const int aq   = tid & 1;
    const float* Ap = A + (size_t)(row0 + arow) * lda;
    const int pq0 = pq(c0 >> 2) * 4;
    const int pq1 = pq((c0 >> 2) + 1) * 4;

    float acc[8][8];
#pragma unroll
    for (int i = 0; i < 8; i++)
#pragma unroll
        for (int j = 0; j < 8; j++) acc[i][j] = 0.f;

    float4 areg[4], wreg[4];
#pragma unroll
    for (int qq = 0; qq < 4; qq++)
        areg[qq] = *(const float4*)(Ap + (aq + 2 * qq) * 4);
#pragma unroll
    for (int q = 0; q < 4; q++) {
        int f = tid + 256 * q;
        wreg[q] = *(const float4*)(W + (size_t)(f >> 5) * 128 + (f & 31) * 4);
    }

    constexpr int NT = KDIM / 32;
    for (int t = 0; t < NT; t++) {
#pragma unroll
        for (int qq = 0; qq < 4; qq++) {
            int kk = (aq + 2 * qq) * 4;
            As[kk + 0][arow] = areg[qq].x;
            As[kk + 1][arow] = areg[qq].y;
            As[kk + 2][arow] = areg[qq].z;
            As[kk + 3][arow] = areg[qq].w;
        }
#pragma unroll
        for (int q = 0; q < 4; q++) {
            int f = tid + 256 * q;
            *(float4*)&Ws[(f >> 5) * 128 + pq(f & 31) * 4] = wreg[q];
        }
        __syncthreads();
        if (t + 1 < NT) {     // prefetch next tile into regs during compute
            int k0 = (t + 1) * 32;
#pragma unroll
            for (int qq = 0; qq < 4; qq++)
                areg[qq] = *(const float4*)(Ap + k0 + (aq + 2 * qq) * 4);
#pragma unroll
            for (int q = 0; q < 4; q++) {
                int f = tid + 256 * q;
                wreg[q] = *(const float4*)(W + (size_t)(k0 + (f >> 5)) * 128 + (f & 31) * 4);
            }
        }
#pragma unroll 2
        for (int kk = 0; kk < 32; kk++) {
            float4 a0 = *(const float4*)&As[kk][r0];
            float4 a1 = *(const float4*)&As[kk][r0 + 4];
            float4 b0 = *(const float4*)&Ws[kk * 128 + pq0];
            float4 b1 = *(const float4*)&Ws[kk * 128 + pq1];
            float a[8] = {a0.x, a0.y, a0.z, a0.w, a1.x, a1.y, a1.z, a1.w};
            float b[8] = {b0.x, b0.y, b0.z, b0.w, b1.x, b1.y, b1.z, b1.w};
#pragma unroll
            for (int i = 0; i < 8; i++)
#pragma unroll
                for (int j = 0; j < 8; j++)
                    acc[i][j] = fmaf(a[i], b[j], acc[i][j]);
        }
        if (t + 1 < NT) __syncthreads();
    }
#pragma unroll
    for (int i = 0; i < 8; i++) {
        int row = row0 + r0 + i;
        if (row < M) {
            float sc = rowscale[row];
            float4 o0 = {acc[i][0]*sc, acc[i][1]*sc, acc[i][2]*sc, acc[i][3]*sc};
            float4 o1 = {acc[i][4]*sc, acc[i][5]*sc, acc[i][6]*sc, acc[i][7]*sc};
            *(float4*)(C + (size_t)row * 128 + c0) = o0;
            *(float4*)(C + (size_t)row * 128 + c0 + 4) = o1;
        }
    }
}

// pooled GEMM, K-split: grid (256 row-blocks, 2 k-halves of 192). A rows gathered
// from XC via sel with fused sigmoid; 512 threads, 4x8 micro-tile, single buffer.
// Staging map: arow=(tid&255)>>1, aq=tid&1, khalf=tid>>8 (wave-uniform) -> 2-way writes.
__global__ __launch_bounds__(512) void k_gemm_gather(const float* __restrict__ XC,
                                                     const int* __restrict__ sel,
                                                     const float* __restrict__ SC,
                                                     const float* __restrict__ rowscale,
                                                     const float* __restrict__ W,
                                                     float* __restrict__ C0,
                                                     float* __restrict__ C1) {
    __shared__ float As[32][132];
    __shared__ float Ws[32 * 128];
    const int tid  = threadIdx.x;
    const int c0 = (tid & 15) * 8;
    const int r0 = (tid >> 4) * 4;
    const int row0 = blockIdx.x * 128;
    const int kbase = blockIdx.y * 192;
    float* __restrict__ C = blockIdx.y ? C1 : C0;
    const int arow  = (tid & 255) >> 1;
    const int aq    = tid & 1;
    const int khalf = tid >> 8;
    const int pq0 = pq(c0 >> 2) * 4;
    const int pq1 = pq((c0 >> 2) + 1) * 4;

    int n = row0 + arow;
    int comm = n >= NP;
    int nl = n - (comm ? NP : 0);
    int b = nl >> 8;
    int old = sel[n];
    const float* srow = XC + (size_t)(b * NPB + comm * 512 + old) * 384 + kbase;
    float scv = SC[comm * 32768 + b * 512 + old];
    float sg = 1.f / (1.f + expf(-scv));

    float acc[4][8];
#pragma unroll
    for (int i = 0; i < 4; i++)
#pragma unroll
        for (int j = 0; j < 8; j++) acc[i][j] = 0.f;

    // thread stages 2 float4 of its row: quads khalf*4 + 2*qq + aq (qq=0,1)
    float4 areg[2], wreg[2];
#pragma unroll
    for (int qq = 0; qq < 2; qq++)
        areg[qq] = *(const float4*)(srow + (khalf * 4 + 2 * qq + aq) * 4);
#pragma unroll
    for (int q = 0; q < 2; q++) {
        int f = tid + 512 * q;
        wreg[q] = *(const float4*)(W + (size_t)(kbase + (f >> 5)) * 128 + (f & 31) * 4);
    }

    constexpr int NT = 6;
    for (int t = 0; t < NT; t++) {
#pragma unroll
        for (int qq = 0; qq < 2; qq++) {
            int kk = (khalf * 4 + 2 * qq + aq) * 4;
            As[kk + 0][arow] = areg[qq].x * sg;
            As[kk + 1][arow] = areg[qq].y * sg;
            As[kk + 2][arow] = areg[qq].z * sg;
            As[kk + 3][arow] = areg[qq].w * sg;
        }
#pragma unroll
        for (int q = 0; q < 2; q++) {
            int f = tid + 512 * q;
            *(float4*)&Ws[(f >> 5) * 128 + pq(f & 31) * 4] = wreg[q];
        }
        __syncthreads();
        if (t + 1 < NT) {
            int k0 = (t + 1) * 32;
#pragma unroll
            for (int qq = 0; qq < 2; qq++)
                areg[qq] = *(const float4*)(srow + k0 + (khalf * 4 + 2 * qq + aq) * 4);
#pragma unroll
            for (int q = 0; q < 2; q++) {
                int f = tid + 512 * q;
                wreg[q] = *(const float4*)(W + (size_t)(kbase + k0 + (f >> 5)) * 128 + (f & 31) * 4);
            }
        }
#pragma unroll 2
        for (int kk = 0; kk < 32; kk++) {
            float4 a0 = *(const float4*)&As[kk][r0];
            float4 b0 = *(const float4*)&Ws[kk * 128 + pq0];
            float4 b1 = *(const float4*)&Ws[kk * 128 + pq1];
            float a[4] = {a0.x, a0.y, a0.z, a0.w};
            float b8[8] = {b0.x, b0.y, b0.z, b0.w, b1.x, b1.y, b1.z, b1.w};
#pragma unroll
            for (int i = 0; i < 4; i++)
#pragma unroll
                for (int j = 0; j < 8; j++)
                    acc[i][j] = fmaf(a[i], b8[j], acc[i][j]);
        }
        if (t + 1 < NT) __syncthreads();
    }
#pragma unroll
    for (int i = 0; i < 4; i++) {
        int row = row0 + r0 + i;
        float sc = rowscale[row];
        float4 o0 = {acc[i][0]*sc, acc[i][1]*sc, acc[i][2]*sc, acc[i][3]*sc};
        float4 o1 = {acc[i][4]*sc, acc[i][5]*sc, acc[i][6]*sc, acc[i][7]*sc};
        *(float4*)(C + (size_t)row * 128 + c0) = o0;
        *(float4*)(C + (size_t)row * 128 + c0 + 4) = o1;
    }
}

// ---------------- GCN aggregation (CSR gather, xw pre-scaled by dis[src]) ----------------
__global__ void k_aggregate4(const float* __restrict__ xwsc, const float* __restrict__ dis,
                             const int* __restrict__ rowstart, const int* __restrict__ csrc,
                             const float* __restrict__ bias, float* __restrict__ XC, int colbase) {
    int xcd  = blockIdx.x & 7;
    int slot = blockIdx.x >> 3;            // 0..1023
    int g    = ((slot >> 6) << 3) | xcd;   // 0..127
    int node = g * 512 + (slot & 63) * 8 + (threadIdx.x >> 5);
    int l    = threadIdx.x & 31;
    const float4* xw4 = (const float4*)xwsc;
    float4 acc = xw4[(size_t)node * 32 + l];
    int e0 = rowstart[node], e1 = rowstart[node + 1];
    for (int e = e0; e < e1; e++) {
        int s = csrc[e];
        float4 u = xw4[(size_t)s * 32 + l];
        acc.x += u.x; acc.y += u.y; acc.z += u.z; acc.w += u.w;
    }
    float di = dis[node];
    float4 b4 = ((const float4*)bias)[l];
    acc.x = fmaxf(acc.x * di + b4.x, 0.f);
    acc.y = fmaxf(acc.y * di + b4.y, 0.f);
    acc.z = fmaxf(acc.z * di + b4.z, 0.f);
    acc.w = fmaxf(acc.w * di + b4.w, 0.f);
    *(float4*)(XC + (size_t)node * 384 + colbase + l * 4) = acc;
}

// pooled variant: sums the two K-split partials inline
__global__ void k_aggregate_pooled(const float* __restrict__ xw0, const float* __restrict__ xw1,
                                   const float* __restrict__ disp,
                                   const int* __restrict__ rowstart, const int* __restrict__ cntp,
                                   const int* __restrict__ csre,
                                   const float* __restrict__ bias, float* __restrict__ H) {
    int xcd  = blockIdx.x & 7;
    int slot = blockIdx.x >> 3;            // 0..511
    int g    = ((slot >> 5) << 3) | xcd;   // 0..127
    int node = g * 256 + (slot & 31) * 8 + (threadIdx.x >> 5);
    int l    = threadIdx.x & 31;
    const float4* x0 = (const float4*)xw0;
    const float4* x1 = (const float4*)xw1;
    float4 p0 = x0[(size_t)node * 32 + l];
    float4 p1 = x1[(size_t)node * 32 + l];
    float4 acc = {p0.x + p1.x, p0.y + p1.y, p0.z + p1.z, p0.w + p1.w};
    int e0 = rowstart[node], n = cntp[node];
    for (int i = 0; i < n; i++) {
        int r = csre[e0 + i];
        float4 u0 = x0[(size_t)r * 32 + l];
        float4 u1 = x1[(size_t)r * 32 + l];
        acc.x += u0.x + u1.x; acc.y += u0.y + u1.y;
        acc.z += u0.z + u1.z; acc.w += u0.w + u1.w;
    }
    float di = disp[node];
    float4 b4 = ((const float4*)bias)[l];
    acc.x = fmaxf(acc.x * di + b4.x, 0.f);
    acc.y = fmaxf(acc.y * di + b4.y, 0.f);
    acc.z = fmaxf(acc.z * di + b4.z, 0.f);
    acc.w = fmaxf(acc.w * di + b4.w, 0.f);
    *(float4*)(H + (size_t)node * 128 + l * 4) = acc;
}

// ---------------- attention pool stage 1 ----------------
__global__ void k_mean_part(const float* __restrict__ XC, float* __restrict__ mpart) {
    int blk = blockIdx.x;              // 0..511
    int gc = blk >> 2, p = blk & 3;
    int seg = ((gc & 1) << 6) | (gc >> 1);
    int c = threadIdx.x;               // 0..383
    int base = gc * 512 + p * 128;
    float s = 0.f;
    for (int i = 0; i < 128; i++) s += XC[(size_t)(base + i) * 384 + c];
    mpart[(size_t)(seg * 4 + p) * 384 + c] = s;
}

__global__ void k_c12(const float* __restrict__ mpart, const float* __restrict__ Wg,
                      float* __restrict__ c12) {
    __shared__ float ms[384];
    int seg = blockIdx.x; int c = threadIdx.x;   // 384 threads
    ms[c] = (mpart[(size_t)(seg * 4 + 0) * 384 + c] + mpart[(size_t)(seg * 4 + 1) * 384 + c] +
             mpart[(size_t)(seg * 4 + 2) * 384 + c] + mpart[(size_t)(seg * 4 + 3) * 384 + c]) *
            (1.0f / 512.0f);
    __syncthreads();
    float s = 0.f;
    for (int k = 0; k < 384; k++) s = fmaf(ms[k], Wg[(size_t)k * 384 + c], s);
    c12[seg * 384 + c] = tanhf(s);
}

__global__ __launch_bounds__(256) void k_attpool1(const float* __restrict__ XC,
                                                  const float* __restrict__ C12,
                                                  float* __restrict__ GP) {
    __shared__ float gps[4][384];
    int blk = blockIdx.x;              // 0..511 (4 per group)
    int gc = blk >> 2, q = blk & 3;
    int seg = ((gc & 1) << 6) | (gc >> 1);
    int w = threadIdx.x >> 6, l = threadIdx.x & 63;
    const float* c12r = C12 + seg * 384;
    float4 cr0 = *(const float4*)(c12r + 4 * l);
    float4 cr1 = (l < 32) ? *(const float4*)(c12r + 256 + 4 * l) : float4{0.f,0.f,0.f,0.f};
    float4 a0 = {0.f,0.f,0.f,0.f}, a1 = {0.f,0.f,0.f,0.f};
    int base = gc * 512 + q * 128 + w * 32;
    for (int it = 0; it < 32; it++) {
        const float* xr = XC + (size_t)(base + it) * 384;
        float4 v0 = *(const float4*)(xr + 4 * l);
        float4 v1 = (l < 32) ? *(const float4*)(xr + 256 + 4 * l) : float4{0.f,0.f,0.f,0.f};
        float s = v0.x*cr0.x + v0.y*cr0.y + v0.z*cr0.z + v0.w*cr0.w
                + v1.x*cr1.x + v1.y*cr1.y + v1.z*cr1.z + v1.w*cr1.w;
        for (int off = 32; off; off >>= 1) s += __shfl_xor(s, off);
        float al = 1.f / (1.f + expf(-s));
        a0.x += v0.x*al; a0.y += v0.y*al; a0.z += v0.z*al; a0.w += v0.w*al;
        a1.x += v1.x*al; a1.y += v1.y*al; a1.z += v1.z*al; a1.w += v1.w*al;
    }
    *(float4*)&gps[w][4 * l] = a0;
    if (l < 32) *(float4*)&gps[w][256 + 4 * l] = a1;
    __syncthreads();
    for (int c = threadIdx.x; c < 384; c += 256) {
        float s = gps[0][c] + gps[1][c] + gps[2][c] + gps[3][c];
        atomicAdd(&GP[seg * 384 + c], s);
    }
}

__global__ void k_pv(const float* __restrict__ gp, const float* __restrict__ Wal,
                     const float* __restrict__ bal, float* __restrict__ pv) {
    int row = blockIdx.x;               // 0..63
    int c   = threadIdx.x;              // 0..767
    float s = bal[c];
    for (int k = 0; k < 768; k++) {
        float v = (k < 384) ? gp[row * 384 + k] : gp[(64 + row) * 384 + (k - 384)];
        s = fmaf(v, Wal[(size_t)k * 768 + c], s);
    }
    pv[row * 768 + c] = s;
}

__global__ void k_pnorm(const float* __restrict__ pv, float* __restrict__ pnorm) {
    int id = blockIdx.x;                // 0..127 : comm = id>>6, b = id&63
    int lane = threadIdx.x;
    int h = id >> 6, b = id & 63;
    const float* p = pv + b * 768 + h * 384;
    float s = 0.f;
    for (int k = lane; k < 384; k += 64) s += p[k] * p[k];
    for (int off = 32; off; off >>= 1) s += __shfl_down(s, off);
    if (lane == 0) pnorm[id] = sqrtf(s);
}

// ---------------- scores (both communities) + per-batch top-K ----------------
__global__ void k_score(const float* __restrict__ XC, const float* __restrict__ pv,
                        const float* __restrict__ pnorm, float* __restrict__ sc) {
    int nl2 = blockIdx.x * 4 + (threadIdx.x >> 6);   // 0..65535
    int lane = threadIdx.x & 63;
    int comm = nl2 >> 15;
    int nl = nl2 & 32767;
    int b = nl >> 9; int i = nl & 511;
    const float* xr = XC + (size_t)(b * NPB + comm * 512 + i) * 384;
    const float* pr = pv + b * 768 + comm * 384;
    float4 x0 = *(const float4*)(xr + 4 * lane);
    float4 p0 = *(const float4*)(pr + 4 * lane);
    float s = x0.x*p0.x + x0.y*p0.y + x0.z*p0.z + x0.w*p0.w;
    if (lane < 32) {
        float4 x1 = *(const float4*)(xr + 256 + 4 * lane);
        float4 p1 = *(const float4*)(pr + 256 + 4 * lane);
        s += x1.x*p1.x + x1.y*p1.y + x1.z*p1.z + x1.w*p1.w;
    }
    for (int off = 32; off; off >>= 1) s += __shfl_down(s, off);
    if (lane == 0) sc[comm * 32768 + nl] = s / pnorm[comm * 64 + b];
}

__global__ void k_topk(const float* __restrict__ sc, int* __restrict__ sel, int* __restrict__ nmap) {
    __shared__ float sv[512];
    __shared__ int   si[512];
    int blk = blockIdx.x;               // 0..127 = comm*64 + b
    int t = threadIdx.x;                // 0..255
    sv[t] = sc[blk * 512 + t];             si[t] = t;
    sv[t + 256] = sc[blk * 512 + t + 256]; si[t + 256] = t + 256;
    __syncthreads();
    for (int k2 = 2; k2 <= 512; k2 <<= 1) {
        for (int j = k2 >> 1; j > 0; j >>= 1) {
            for (int i = t; i < 512; i += 256) {
                int l = i ^ j;
                if (l > i) {
                    bool desc = ((i & k2) == 0);
                    float a = sv[i], bb2 = sv[l];
                    bool sw = desc ? (a < bb2) : (a > bb2);
                    if (sw) {
                        sv[i] = bb2; sv[l] = a;
                        int tmp = si[i]; si[i] = si[l]; si[l] = tmp;
                    }
                }
            }
            __syncthreads();
        }
    }
    sel[blk * 256 + t] = si[t];
    nmap[blk * 512 + si[t]] = blk * 256 + t;
    nmap[blk * 512 + si[t + 256]] = -1;
}

// ---------------- final attention pools ----------------
__global__ void k_meanf(const float* __restrict__ H, float* __restrict__ mean) {
    int b = blockIdx.x; int c = threadIdx.x;
    float s = 0.f;
    for (int i = 0; i < 256; i++) s += H[(size_t)(b * 256 + i) * 128 + c];
    mean[b * 128 + c] = s * (1.0f / 256.0f);
}

__global__ void k_cfin(const float* __restrict__ mean, const float* __restrict__ Wg,
                       float* __restrict__ cf) {
    __shared__ float ms[128];
    int b = blockIdx.x; int c = threadIdx.x;
    ms[c] = mean[b * 128 + c];
    __syncthreads();
    float s = 0.f;
    for (int k = 0; k < 128; k++) s = fmaf(ms[k], Wg[k * 128 + c], s);
    cf[b * 128 + c] = tanhf(s);
}

__global__ void k_alphaf(const float* __restrict__ H, const float* __restrict__ cf,
                         float* __restrict__ al) {
    int node = blockIdx.x * 4 + (threadIdx.x >> 6);
    int lane = threadIdx.x & 63;
    int b = node >> 8;
    float s = 0.f;
    if (lane < 32) {
        float4 h = *(const float4*)(H + (size_t)node * 128 + 4 * lane);
        float4 c = *(const float4*)(cf + b * 128 + 4 * lane);
        s = h.x*c.x + h.y*c.y + h.z*c.z + h.w*c.w;
    }
    for (int off = 32; off; off >>= 1) s += __shfl_down(s, off);
    if (lane == 0) al[node] = 1.f / (1.f + expf(-s));
}

__global__ void k_gfin(const float* __restrict__ H, const float* __restrict__ al,
                       float* __restrict__ g) {
    int seg = blockIdx.x; int c = threadIdx.x;
    int b = seg & 63, comm = seg >> 6;
    float s = 0.f;
    for (int i = 0; i < 256; i++) { int n = seg * 256 + i; s += H[(size_t)n * 128 + c] * al[n]; }
    g[b * 256 + comm * 128 + c] = s;
}

// ---------------- MLP head ----------------
__global__ void k_mlp(const float* __restrict__ G,
                      const float* __restrict__ Wl1, const float* __restrict__ bl1,
                      const float* __restrict__ Wl2, const float* __restrict__ bl2,
                      const float* __restrict__ Wl3, const float* __restrict__ bl3,
                      float* __restrict__ out) {
    __shared__ float t1[128], t2[64];
    int b = blockIdx.x; int t = threadIdx.x;
    float s = bl1[t];
    for (int k = 0; k < 256; k++) s = fmaf(G[b * 256 + k], Wl1[k * 128 + t], s);
    t1[t] = fmaxf(s, 0.f);
    __syncthreads();
    if (t < 64) {
        float s2 = bl2[t];
        for (int k = 0; k < 128; k++) s2 = fmaf(t1[k], Wl2[k * 64 + t], s2);
        t2[t] = fmaxf(s2, 0.f);
    }
    __syncthreads();
    if (t < 2) {
        float s3 = bl3[t];
        for (int k = 0; k < 64; k++) s3 = fmaf(t2[k], Wl3[k * 2 + t], s3);
        out[b * 2 + t] = s3;
    }
}

// ---------------- launch ----------------
extern "C" void kernel_launch(void* const* d_in, const int* in_sizes, int n_in,
                              void* d_out, int out_size, void* d_ws, size_t ws_size,
                              hipStream_t stream) {
    const float* x       = (const float*)d_in[0];
    const int*   src_all = (const int*)d_in[1];
    const int*   dst_all = (const int*)d_in[2];
    const int*   src_c1  = (const int*)d_in[3];
    const int*   dst_c1  = (const int*)d_in[4];
    const int*   src_c2  = (const int*)d_in[5];
    const int*   dst_c2  = (const int*)d_in[6];
    const float* W1 = (const float*)d_in[7];   const float* b1 = (const float*)d_in[8];
    const float* W2 = (const float*)d_in[9];   const float* b2 = (const float*)d_in[10];
    const float* W3 = (const float*)d_in[11];  const float* b3 = (const float*)d_in[12];
    const float* Wg_att = (const float*)d_in[13];
    const float* Wal = (const float*)d_in[14]; const float* bal = (const float*)d_in[15];
    const float* Wf  = (const float*)d_in[16]; const float* bf  = (const float*)d_in[17];
    const float* Wg_fin = (const float*)d_in[18];
    const float* Wl1 = (const float*)d_in[19]; const float* bl1 = (const float*)d_in[20];
    const float* Wl2 = (const float*)d_in[21]; const float* bl2 = (const float*)d_in[22];
    const float* Wl3 = (const float*)d_in[23]; const float* bl3 = (const float*)d_in[24];
    float* out = (float*)d_out;

    // ---- workspace layout (floats) ----
    float* f = (float*)d_ws;
    size_t o = 0;
    float* XC   = f + o; o += (size_t)NN * 384;
    float* SCR  = f + o; o += (size_t)NN * 128;     // xw*dis; later 2 K-split partials (2 x NP2 x 128)
    float* H    = f + o; o += (size_t)NP2 * 128;
    int* ROWSTART = (int*)(f + o); o += 65552;
    int* CSRC     = (int*)(f + o); o += EALL;
    int* CNTP     = (int*)(f + o); o += NP2;
    float* DIS    = f + o; o += NN;
    float* MPART  = f + o; o += 512 * 384;
    float* C12    = f + o; o += 128 * 384;
    float* GP     = f + o; o += 128 * 384;
    float* PV     = f + o; o += 64 * 768;
    float* PNORM  = f + o; o += 128;
    float* SC     = f + o; o += 65536;
    int* SEL      = (int*)(f + o); o += NP2;
    int* NMAP     = (int*)(f + o); o += 65536;
    float* DISP   = f + o; o += NP2;
    float* MEANF  = f + o; o += 128 * 128;
    float* CFIN   = f + o; o += 128 * 128;
    float* ALF    = f + o; o += NP2;
    float* G12    = f + o; o += 64 * 256;
    size_t needed_bytes = o * sizeof(float);
    if (ws_size < needed_bytes) return;

    float* XWP0 = SCR;                            // K-half 0 partial
    float* XWP1 = SCR + (size_t)NP2 * 128;        // K-half 1 partial

    // ---- full-graph CSR + degrees ----
    k_build_csr<<<128, 256, 0, stream>>>(src_all, dst_all, ROWSTART, CSRC, DIS);

    // ---- 3 GCN layers ----
    k_gemm_tile<128><<<NN / 128, 256, 0, stream>>>(x, 128, W1, DIS, SCR, NN);
    k_aggregate4<<<NN / 8, 256, 0, stream>>>(SCR, DIS, ROWSTART, CSRC, b1, XC, 0);
    k_gemm_tile<128><<<NN / 128, 256, 0, stream>>>(XC + 0, 384, W2, DIS, SCR, NN);
    k_aggregate4<<<NN / 8, 256, 0, stream>>>(SCR, DIS, ROWSTART, CSRC, b2, XC, 128);
    k_gemm_tile<128><<<NN / 128, 256, 0, stream>>>(XC + 128, 384, W3, DIS, SCR, NN);
    k_aggregate4<<<NN / 8, 256, 0, stream>>>(SCR, DIS, ROWSTART, CSRC, b3, XC, 256);

    // ---- attention pool over communities ----
    k_mean_part<<<512, 384, 0, stream>>>(XC, MPART);
    k_c12<<<128, 384, 0, stream>>>(MPART, Wg_att, C12);
    hipMemsetAsync(GP, 0, 128 * 384 * sizeof(float), stream);
    k_attpool1<<<512, 256, 0, stream>>>(XC, C12, GP);
    k_pv<<<64, 768, 0, stream>>>(GP, Wal, bal, PV);
    k_pnorm<<<128, 64, 0, stream>>>(PV, PNORM);

    // ---- scores + top-K ----
    k_score<<<65536 / 4, 256, 0, stream>>>(XC, PV, PNORM, SC);
    k_topk<<<128, 256, 0, stream>>>(SC, SEL, NMAP);

    // ---- pooled graph build ----
    k_build_csr_pooled<<<128, 256, 0, stream>>>(src_c1, dst_c1, src_c2, dst_c2,
                                                NMAP, ROWSTART, CNTP, CSRC, DISP);

    // ---- pooled GCN (K-split gathered GEMM + fused-sum CSR aggregate) ----
    k_gemm_gather<<<dim3(NP2 / 128, 2), 512, 0, stream>>>(XC, SEL, SC, DISP, Wf, XWP0, XWP1);
    k_aggregate_pooled<<<NP2 / 8, 256, 0, stream>>>(XWP0, XWP1, DISP, ROWSTART, CNTP, CSRC, bf, H);

    // ---- final attention pools ----
    k_meanf<<<128, 128, 0, stream>>>(H, MEANF);
    k_cfin<<<128, 128, 0, stream>>>(MEANF, Wg_fin, CFIN);
    k_alphaf<<<NP2 / 4, 256, 0, stream>>>(H, CFIN, ALF);
    k_gfin<<<128, 128, 0, stream>>>(H, ALF, G12);

    // ---- MLP head ----
    k_mlp<<<64, 128, 0, stream>>>(G12, Wl1, bl1, Wl2, bl2, Wl3, bl3, out);
}

// Round 7
// 641.420 us; speedup vs baseline: 1.0572x; 1.0572x over previous
//
#include <hip/hip_runtime.h>
#include <math.h>

// ---------------- constants ----------------
constexpr int BB   = 64;
constexpr int NPB  = 1024;            // nodes per batch graph (N1+N2)
constexpr int NN   = BB * NPB;        // 65536 total nodes
constexpr int EALL = 1048576;         // total edges (both communities)
constexpr int EC   = 524288;          // edges per community
constexpr int EPG  = 8192;            // edges per (batch,community) group == N1*DEG
constexpr int KTOP = 256;             // K1 == K2
constexpr int NP   = BB * KTOP;       // 16384 pooled nodes per community
constexpr int NP2  = 2 * NP;          // 32768 pooled nodes total

// physical quad swizzle for Ws: bijective on 0..31; even/odd read sequences land 2-way (free)
__device__ __forceinline__ int pq(int q) { return q ^ (q >> 3); }

// ---------------- full-graph CSR build: per-group LDS counting sort ----------------
__global__ __launch_bounds__(256) void k_build_csr(const int* __restrict__ src_all,
                                                   const int* __restrict__ dst_all,
                                                   int* __restrict__ rowstart,
                                                   int* __restrict__ csrc,
                                                   float* __restrict__ dis) {
    __shared__ int cnt[512];
    __shared__ int rs[512];
    __shared__ int wsum[4];
    __shared__ int stage[EPG];
    const int g = blockIdx.x;
    const int b = g >> 1, c = g & 1;
    const int ebase  = c * EC + b * EPG;
    const int region = g * EPG;
    const int nbase  = g * 512;
    const int t = threadIdx.x;
    const int lane = t & 63, w = t >> 6;

    cnt[t] = 0; cnt[t + 256] = 0;
    __syncthreads();
    for (int i = 0; i < 32; i++) {
        int d = dst_all[ebase + t + 256 * i] & 511;
        atomicAdd(&cnt[d], 1);
    }
    __syncthreads();
    int v0 = cnt[2 * t], v1 = cnt[2 * t + 1];
    int p = v0 + v1;
    int incl = p;
    for (int off = 1; off < 64; off <<= 1) {
        int u = __shfl_up(incl, off);
        if (lane >= off) incl += u;
    }
    if (lane == 63) wsum[w] = incl;
    __syncthreads();
    int base = 0;
    for (int i = 0; i < w; i++) base += wsum[i];
    int excl = base + incl - p;
    rs[2 * t] = excl;
    rs[2 * t + 1] = excl + v0;
    rowstart[nbase + 2 * t]     = region + excl;
    rowstart[nbase + 2 * t + 1] = region + excl + v0;
    dis[nbase + 2 * t]     = 1.0f / sqrtf((float)v0 + 1.0f);
    dis[nbase + 2 * t + 1] = 1.0f / sqrtf((float)v1 + 1.0f);
    if (g == 127 && t == 0) rowstart[NN] = EALL;
    __syncthreads();
    for (int i = 0; i < 32; i++) {
        int e = ebase + t + 256 * i;
        int d = dst_all[e] & 511;
        int pp = atomicAdd(&rs[d], 1);
        stage[pp] = src_all[e];
    }
    __syncthreads();
    for (int i = 0; i < 32; i++)
        csrc[region + t + 256 * i] = stage[t + 256 * i];
}

// ---------------- pooled CSR build ----------------
__global__ __launch_bounds__(256) void k_build_csr_pooled(const int* __restrict__ s1,
                                                          const int* __restrict__ d1,
                                                          const int* __restrict__ s2,
                                                          const int* __restrict__ d2,
                                                          const int* __restrict__ nmap,
                                                          int* __restrict__ rowstart,
                                                          int* __restrict__ cntp,
                                                          int* __restrict__ csre,
                                                          float* __restrict__ disp) {
    __shared__ int cnt[256];
    __shared__ int rs[256];
    __shared__ int wsum[4];
    __shared__ int stage[EPG];
    const int g = blockIdx.x;
    const int c = g >> 6, b = g & 63;
    const int* ss = c ? s2 : s1;
    const int* dd = c ? d2 : d1;
    const int* nm = nmap + c * 32768;
    const int ebase  = b * EPG;
    const int region = g * EPG;
    const int nbase  = g * 256;
    const int t = threadIdx.x;
    const int lane = t & 63, w = t >> 6;

    cnt[t] = 0;
    __syncthreads();
    for (int i = 0; i < 32; i++) {
        int e = ebase + t + 256 * i;
        int r = nm[ss[e]], cc = nm[dd[e]];
        if (r >= 0 && cc >= 0) atomicAdd(&cnt[cc & 255], 1);
    }
    __syncthreads();
    int v = cnt[t];
    int incl = v;
    for (int off = 1; off < 64; off <<= 1) {
        int u = __shfl_up(incl, off);
        if (lane >= off) incl += u;
    }
    if (lane == 63) wsum[w] = incl;
    __syncthreads();
    int base = 0;
    for (int i = 0; i < w; i++) base += wsum[i];
    int excl = base + incl - v;
    rs[t] = excl;
    rowstart[nbase + t] = region + excl;
    cntp[nbase + t] = v;
    disp[nbase + t] = 1.0f / sqrtf((float)v + 1.0f);
    __syncthreads();
    for (int i = 0; i < 32; i++) {
        int e = ebase + t + 256 * i;
        int r = nm[ss[e]], cc = nm[dd[e]];
        if (r >= 0 && cc >= 0) {
            int pp = atomicAdd(&rs[cc & 255], 1);
            stage[pp] = r;
        }
    }
    __syncthreads();
    for (int i = 0; i < 32; i++)
        csre[region + t + 256 * i] = stage[t + 256 * i];
}

// ---------------- GEMM: C[M x 128] = A[M x KDIM] @ W[KDIM x 128], row-scaled ----------------
// single-buffered, reg-prefetch; As stride 132 (2-way writes, aligned b128 reads);
// Ws quad-swizzled pq (2-way reads/writes).
template <int KDIM>
__global__ __launch_bounds__(256) void k_gemm_tile(const float* __restrict__ A, int lda,
                                                   const float* __restrict__ W,
                                                   const float* __restrict__ rowscale,
                                                   float* __restrict__ C, int M) {
    __shared__ float As[32][132];
    __shared__ float Ws[32 * 128];
    const int tid  = threadIdx.x;
    const int c0 = (tid & 15) * 8;
    const int r0 = (tid >> 4) * 8;
    const int row0 = blockIdx.x * 128;
    const int arow = tid >> 1;
    const int aq   = tid & 1;
    const float* Ap = A + (size_t)(row0 + arow) * lda;
    const int pq0 = pq(c0 >> 2) * 4;
    const int pq1 = pq((c0 >> 2) + 1) * 4;

    float acc[8][8];
#pragma unroll
    for (int i = 0; i < 8; i++)
#pragma unroll
        for (int j = 0; j < 8; j++) acc[i][j] = 0.f;

    float4 areg[4], wreg[4];
#pragma unroll
    for (int qq = 0; qq < 4; qq++)
        areg[qq] = *(const float4*)(Ap + (aq + 2 * qq) * 4);
#pragma unroll
    for (int q = 0; q < 4; q++) {
        int f = tid + 256 * q;
        wreg[q] = *(const float4*)(W + (size_t)(f >> 5) * 128 + (f & 31) * 4);
    }

    constexpr int NT = KDIM / 32;
    for (int t = 0; t < NT; t++) {
#pragma unroll
        for (int qq = 0; qq < 4; qq++) {
            int kk = (aq + 2 * qq) * 4;
            As[kk + 0][arow] = areg[qq].x;
            As[kk + 1][arow] = areg[qq].y;
            As[kk + 2][arow] = areg[qq].z;
            As[kk + 3][arow] = areg[qq].w;
        }
#pragma unroll
        for (int q = 0; q < 4; q++) {
            int f = tid + 256 * q;
            *(float4*)&Ws[(f >> 5) * 128 + pq(f & 31) * 4] = wreg[q];
        }
        __syncthreads();
        if (t + 1 < NT) {
            int k0 = (t + 1) * 32;
#pragma unroll
            for (int qq = 0; qq < 4; qq++)
                areg[qq] = *(const float4*)(Ap + k0 + (aq + 2 * qq) * 4);
#pragma unroll
            for (int q = 0; q < 4; q++) {
                int f = tid + 256 * q;
                wreg[q] = *(const float4*)(W + (size_t)(k0 + (f >> 5)) * 128 + (f & 31) * 4);
            }
        }
#pragma unroll 2
        for (int kk = 0; kk < 32; kk++) {
            float4 a0 = *(const float4*)&As[kk][r0];
            float4 a1 = *(const float4*)&As[kk][r0 + 4];
            float4 b0 = *(const float4*)&Ws[kk * 128 + pq0];
            float4 b1 = *(const float4*)&Ws[kk * 128 + pq1];
            float a[8] = {a0.x, a0.y, a0.z, a0.w, a1.x, a1.y, a1.z, a1.w};
            float b[8] = {b0.x, b0.y, b0.z, b0.w, b1.x, b1.y, b1.z, b1.w};
#pragma unroll
            for (int i = 0; i < 8; i++)
#pragma unroll
                for (int j = 0; j < 8; j++)
                    acc[i][j] = fmaf(a[i], b[j], acc[i][j]);
        }
        if (t + 1 < NT) __syncthreads();
    }
#pragma unroll
    for (int i = 0; i < 8; i++) {
        int row = row0 + r0 + i;
        if (row < M) {
            float sc = rowscale[row];
            float4 o0 = {acc[i][0]*sc, acc[i][1]*sc, acc[i][2]*sc, acc[i][3]*sc};
            float4 o1 = {acc[i][4]*sc, acc[i][5]*sc, acc[i][6]*sc, acc[i][7]*sc};
            *(float4*)(C + (size_t)row * 128 + c0) = o0;
            *(float4*)(C + (size_t)row * 128 + c0 + 4) = o1;
        }
    }
}

// pooled GEMM, K-split: grid (256 row-blocks, 2 k-halves of 192).
// 256 threads, 8x8 micro-tile (half the LDS reads per FMA of the 4x8 shape).
__global__ __launch_bounds__(256) void k_gemm_gather(const float* __restrict__ XC,
                                                     const int* __restrict__ sel,
                                                     const float* __restrict__ SC,
                                                     const float* __restrict__ rowscale,
                                                     const float* __restrict__ W,
                                                     float* __restrict__ C0,
                                                     float* __restrict__ C1) {
    __shared__ float As[32][132];
    __shared__ float Ws[32 * 128];
    const int tid  = threadIdx.x;
    const int c0 = (tid & 15) * 8;
    const int r0 = (tid >> 4) * 8;
    const int row0 = blockIdx.x * 128;
    const int kbase = blockIdx.y * 192;
    float* __restrict__ C = blockIdx.y ? C1 : C0;
    const int arow = tid >> 1;
    const int aq   = tid & 1;
    const int pq0 = pq(c0 >> 2) * 4;
    const int pq1 = pq((c0 >> 2) + 1) * 4;

    int n = row0 + arow;
    int comm = n >= NP;
    int nl = n - (comm ? NP : 0);
    int b = nl >> 8;
    int old = sel[n];
    const float* srow = XC + (size_t)(b * NPB + comm * 512 + old) * 384 + kbase;
    float scv = SC[comm * 32768 + b * 512 + old];
    float sg = 1.f / (1.f + expf(-scv));

    float acc[8][8];
#pragma unroll
    for (int i = 0; i < 8; i++)
#pragma unroll
        for (int j = 0; j < 8; j++) acc[i][j] = 0.f;

    float4 areg[4], wreg[4];
#pragma unroll
    for (int qq = 0; qq < 4; qq++)
        areg[qq] = *(const float4*)(srow + (aq + 2 * qq) * 4);
#pragma unroll
    for (int q = 0; q < 4; q++) {
        int f = tid + 256 * q;
        wreg[q] = *(const float4*)(W + (size_t)(kbase + (f >> 5)) * 128 + (f & 31) * 4);
    }

    constexpr int NT = 6;
    for (int t = 0; t < NT; t++) {
#pragma unroll
        for (int qq = 0; qq < 4; qq++) {
            int kk = (aq + 2 * qq) * 4;
            As[kk + 0][arow] = areg[qq].x * sg;
            As[kk + 1][arow] = areg[qq].y * sg;
            As[kk + 2][arow] = areg[qq].z * sg;
            As[kk + 3][arow] = areg[qq].w * sg;
        }
#pragma unroll
        for (int q = 0; q < 4; q++) {
            int f = tid + 256 * q;
            *(float4*)&Ws[(f >> 5) * 128 + pq(f & 31) * 4] = wreg[q];
        }
        __syncthreads();
        if (t + 1 < NT) {
            int k0 = (t + 1) * 32;
#pragma unroll
            for (int qq = 0; qq < 4; qq++)
                areg[qq] = *(const float4*)(srow + k0 + (aq + 2 * qq) * 4);
#pragma unroll
            for (int q = 0; q < 4; q++) {
                int f = tid + 256 * q;
                wreg[q] = *(const float4*)(W + (size_t)(kbase + k0 + (f >> 5)) * 128 + (f & 31) * 4);
            }
        }
#pragma unroll 2
        for (int kk = 0; kk < 32; kk++) {
            float4 a0 = *(const float4*)&As[kk][r0];
            float4 a1 = *(const float4*)&As[kk][r0 + 4];
            float4 b0 = *(const float4*)&Ws[kk * 128 + pq0];
            float4 b1 = *(const float4*)&Ws[kk * 128 + pq1];
            float a[8] = {a0.x, a0.y, a0.z, a0.w, a1.x, a1.y, a1.z, a1.w};
            float b8[8] = {b0.x, b0.y, b0.z, b0.w, b1.x, b1.y, b1.z, b1.w};
#pragma unroll
            for (int i = 0; i < 8; i++)
#pragma unroll
                for (int j = 0; j < 8; j++)
                    acc[i][j] = fmaf(a[i], b8[j], acc[i][j]);
        }
        if (t + 1 < NT) __syncthreads();
    }
#pragma unroll
    for (int i = 0; i < 8; i++) {
        int row = row0 + r0 + i;
        float sc = rowscale[row];
        float4 o0 = {acc[i][0]*sc, acc[i][1]*sc, acc[i][2]*sc, acc[i][3]*sc};
        float4 o1 = {acc[i][4]*sc, acc[i][5]*sc, acc[i][6]*sc, acc[i][7]*sc};
        *(float4*)(C + (size_t)row * 128 + c0) = o0;
        *(float4*)(C + (size_t)row * 128 + c0 + 4) = o1;
    }
}

// ---------------- GCN aggregation + fused column-mean partials ----------------
__global__ void k_aggregate4(const float* __restrict__ xwsc, const float* __restrict__ dis,
                             const int* __restrict__ rowstart, const int* __restrict__ csrc,
                             const float* __restrict__ bias, float* __restrict__ XC, int colbase,
                             float* __restrict__ msum) {
    __shared__ float redf[8][128];
    int xcd  = blockIdx.x & 7;
    int slot = blockIdx.x >> 3;            // 0..1023
    int g    = ((slot >> 6) << 3) | xcd;   // 0..127
    int node = g * 512 + (slot & 63) * 8 + (threadIdx.x >> 5);
    int l    = threadIdx.x & 31;
    const float4* xw4 = (const float4*)xwsc;
    float4 acc = xw4[(size_t)node * 32 + l];
    int e0 = rowstart[node], e1 = rowstart[node + 1];
    for (int e = e0; e < e1; e++) {
        int s = csrc[e];
        float4 u = xw4[(size_t)s * 32 + l];
        acc.x += u.x; acc.y += u.y; acc.z += u.z; acc.w += u.w;
    }
    float di = dis[node];
    float4 b4 = ((const float4*)bias)[l];
    acc.x = fmaxf(acc.x * di + b4.x, 0.f);
    acc.y = fmaxf(acc.y * di + b4.y, 0.f);
    acc.z = fmaxf(acc.z * di + b4.z, 0.f);
    acc.w = fmaxf(acc.w * di + b4.w, 0.f);
    *(float4*)(XC + (size_t)node * 384 + colbase + l * 4) = acc;
    // fused mean partials (column sums of the 8 rows in this block)
    *(float4*)&redf[threadIdx.x >> 5][l * 4] = acc;
    __syncthreads();
    if (threadIdx.x < 128) {
        int c = threadIdx.x;
        float s = 0.f;
#pragma unroll
        for (int r = 0; r < 8; r++) s += redf[r][c];
        atomicAdd(&msum[g * 384 + colbase + c], s);
    }
}

// pooled variant: sums K-split partials inline + fused H-mean partials
__global__ void k_aggregate_pooled(const float* __restrict__ xw0, const float* __restrict__ xw1,
                                   const float* __restrict__ disp,
                                   const int* __restrict__ rowstart, const int* __restrict__ cntp,
                                   const int* __restrict__ csre,
                                   const float* __restrict__ bias, float* __restrict__ H,
                                   float* __restrict__ meansum) {
    __shared__ float redf[8][128];
    int xcd  = blockIdx.x & 7;
    int slot = blockIdx.x >> 3;            // 0..511
    int g    = ((slot >> 5) << 3) | xcd;   // 0..127
    int node = g * 256 + (slot & 31) * 8 + (threadIdx.x >> 5);
    int l    = threadIdx.x & 31;
    const float4* x0 = (const float4*)xw0;
    const float4* x1 = (const float4*)xw1;
    float4 p0 = x0[(size_t)node * 32 + l];
    float4 p1 = x1[(size_t)node * 32 + l];
    float4 acc = {p0.x + p1.x, p0.y + p1.y, p0.z + p1.z, p0.w + p1.w};
    int e0 = rowstart[node], n = cntp[node];
    for (int i = 0; i < n; i++) {
        int r = csre[e0 + i];
        float4 u0 = x0[(size_t)r * 32 + l];
        float4 u1 = x1[(size_t)r * 32 + l];
        acc.x += u0.x + u1.x; acc.y += u0.y + u1.y;
        acc.z += u0.z + u1.z; acc.w += u0.w + u1.w;
    }
    float di = disp[node];
    float4 b4 = ((const float4*)bias)[l];
    acc.x = fmaxf(acc.x * di + b4.x, 0.f);
    acc.y = fmaxf(acc.y * di + b4.y, 0.f);
    acc.z = fmaxf(acc.z * di + b4.z, 0.f);
    acc.w = fmaxf(acc.w * di + b4.w, 0.f);
    *(float4*)(H + (size_t)node * 128 + l * 4) = acc;
    // fused mean partials
    *(float4*)&redf[threadIdx.x >> 5][l * 4] = acc;
    __syncthreads();
    if (threadIdx.x < 128) {
        int c = threadIdx.x;
        float s = 0.f;
#pragma unroll
        for (int r = 0; r < 8; r++) s += redf[r][c];
        atomicAdd(&meansum[g * 128 + c], s);
    }
}

// ---------------- attention pool stage 1 ----------------
// c12 from fused column sums (msum indexed by group g)
__global__ void k_c12(const float* __restrict__ msum, const float* __restrict__ Wg,
                      float* __restrict__ c12) {
    __shared__ float ms[384];
    int seg = blockIdx.x; int c = threadIdx.x;   // 384 threads
    int g = ((seg & 63) << 1) | (seg >> 6);
    ms[c] = msum[g * 384 + c] * (1.0f / 512.0f);
    __syncthreads();
    float s = 0.f;
    for (int k = 0; k < 384; k++) s = fmaf(ms[k], Wg[(size_t)k * 384 + c], s);
    c12[seg * 384 + c] = tanhf(s);
}

__global__ __launch_bounds__(256) void k_attpool1(const float* __restrict__ XC,
                                                  const float* __restrict__ C12,
                                                  float* __restrict__ GP) {
    __shared__ float gps[4][384];
    int blk = blockIdx.x;              // 0..511 (4 per group)
    int gc = blk >> 2, q = blk & 3;
    int seg = ((gc & 1) << 6) | (gc >> 1);
    int w = threadIdx.x >> 6, l = threadIdx.x & 63;
    const float* c12r = C12 + seg * 384;
    float4 cr0 = *(const float4*)(c12r + 4 * l);
    float4 cr1 = (l < 32) ? *(const float4*)(c12r + 256 + 4 * l) : float4{0.f,0.f,0.f,0.f};
    float4 a0 = {0.f,0.f,0.f,0.f}, a1 = {0.f,0.f,0.f,0.f};
    int base = gc * 512 + q * 128 + w * 32;
    for (int it = 0; it < 32; it++) {
        const float* xr = XC + (size_t)(base + it) * 384;
        float4 v0 = *(const float4*)(xr + 4 * l);
        float4 v1 = (l < 32) ? *(const float4*)(xr + 256 + 4 * l) : float4{0.f,0.f,0.f,0.f};
        float s = v0.x*cr0.x + v0.y*cr0.y + v0.z*cr0.z + v0.w*cr0.w
                + v1.x*cr1.x + v1.y*cr1.y + v1.z*cr1.z + v1.w*cr1.w;
        for (int off = 32; off; off >>= 1) s += __shfl_xor(s, off);
        float al = 1.f / (1.f + expf(-s));
        a0.x += v0.x*al; a0.y += v0.y*al; a0.z += v0.z*al; a0.w += v0.w*al;
        a1.x += v1.x*al; a1.y += v1.y*al; a1.z += v1.z*al; a1.w += v1.w*al;
    }
    *(float4*)&gps[w][4 * l] = a0;
    if (l < 32) *(float4*)&gps[w][256 + 4 * l] = a1;
    __syncthreads();
    for (int c = threadIdx.x; c < 384; c += 256) {
        float s = gps[0][c] + gps[1][c] + gps[2][c] + gps[3][c];
        atomicAdd(&GP[seg * 384 + c], s);
    }
}

// pv + fused pnorm
__global__ void k_pv(const float* __restrict__ gp, const float* __restrict__ Wal,
                     const float* __restrict__ bal, float* __restrict__ pv,
                     float* __restrict__ pnorm) {
    __shared__ float red[768];
    int row = blockIdx.x;               // 0..63
    int c   = threadIdx.x;              // 0..767
    float s = bal[c];
    for (int k = 0; k < 768; k++) {
        float v = (k < 384) ? gp[row * 384 + k] : gp[(64 + row) * 384 + (k - 384)];
        s = fmaf(v, Wal[(size_t)k * 768 + c], s);
    }
    pv[row * 768 + c] = s;
    red[c] = s * s;
    __syncthreads();
    int wv = c >> 6, ln = c & 63;
    if (wv < 2) {
        float s2 = 0.f;
#pragma unroll
        for (int i = 0; i < 6; i++) s2 += red[wv * 384 + ln + 64 * i];
        for (int off = 32; off; off >>= 1) s2 += __shfl_down(s2, off);
        if (ln == 0) pnorm[wv * 64 + row] = sqrtf(s2);
    }
}

// ---------------- scores (both communities) + per-batch top-K ----------------
__global__ void k_score(const float* __restrict__ XC, const float* __restrict__ pv,
                        const float* __restrict__ pnorm, float* __restrict__ sc) {
    int nl2 = blockIdx.x * 4 + (threadIdx.x >> 6);   // 0..65535
    int lane = threadIdx.x & 63;
    int comm = nl2 >> 15;
    int nl = nl2 & 32767;
    int b = nl >> 9; int i = nl & 511;
    const float* xr = XC + (size_t)(b * NPB + comm * 512 + i) * 384;
    const float* pr = pv + b * 768 + comm * 384;
    float4 x0 = *(const float4*)(xr + 4 * lane);
    float4 p0 = *(const float4*)(pr + 4 * lane);
    float s = x0.x*p0.x + x0.y*p0.y + x0.z*p0.z + x0.w*p0.w;
    if (lane < 32) {
        float4 x1 = *(const float4*)(xr + 256 + 4 * lane);
        float4 p1 = *(const float4*)(pr + 256 + 4 * lane);
        s += x1.x*p1.x + x1.y*p1.y + x1.z*p1.z + x1.w*p1.w;
    }
    for (int off = 32; off; off >>= 1) s += __shfl_down(s, off);
    if (lane == 0) sc[comm * 32768 + nl] = s / pnorm[comm * 64 + b];
}

__global__ void k_topk(const float* __restrict__ sc, int* __restrict__ sel, int* __restrict__ nmap) {
    __shared__ float sv[512];
    __shared__ int   si[512];
    int blk = blockIdx.x;               // 0..127 = comm*64 + b
    int t = threadIdx.x;                // 0..255
    sv[t] = sc[blk * 512 + t];             si[t] = t;
    sv[t + 256] = sc[blk * 512 + t + 256]; si[t + 256] = t + 256;
    __syncthreads();
    for (int k2 = 2; k2 <= 512; k2 <<= 1) {
        for (int j = k2 >> 1; j > 0; j >>= 1) {
            for (int i = t; i < 512; i += 256) {
                int l = i ^ j;
                if (l > i) {
                    bool desc = ((i & k2) == 0);
                    float a = sv[i], bb2 = sv[l];
                    bool sw = desc ? (a < bb2) : (a > bb2);
                    if (sw) {
                        sv[i] = bb2; sv[l] = a;
                        int tmp = si[i]; si[i] = si[l]; si[l] = tmp;
                    }
                }
            }
            __syncthreads();
        }
    }
    sel[blk * 256 + t] = si[t];
    nmap[blk * 512 + si[t]] = blk * 256 + t;
    nmap[blk * 512 + si[t + 256]] = -1;
}

// ---------------- final attention pool (fused alpha + weighted segment sum) ----------------
__global__ void k_cfin(const float* __restrict__ meansum, const float* __restrict__ Wg,
                       float* __restrict__ cf) {
    __shared__ float ms[128];
    int b = blockIdx.x; int c = threadIdx.x;
    ms[c] = meansum[b * 128 + c] * (1.0f / 256.0f);
    __syncthreads();
    float s = 0.f;
    for (int k = 0; k < 128; k++) s = fmaf(ms[k], Wg[k * 128 + c], s);
    cf[b * 128 + c] = tanhf(s);
}

__global__ __launch_bounds__(256) void k_attpool_fin(const float* __restrict__ H,
                                                     const float* __restrict__ cf,
                                                     float* __restrict__ g12) {
    __shared__ float gps[4][128];
    int seg = blockIdx.x;               // 0..127 = comm*64 + b
    int w = threadIdx.x >> 6, l = threadIdx.x & 63;
    const float2 cfl = *(const float2*)(cf + seg * 128 + 2 * l);
    float2 acc = {0.f, 0.f};
    int base = seg * 256 + w * 64;
    for (int it = 0; it < 64; it++) {
        const float2 h = *(const float2*)(H + (size_t)(base + it) * 128 + 2 * l);
        float s = h.x * cfl.x + h.y * cfl.y;
        for (int off = 32; off; off >>= 1) s += __shfl_xor(s, off);
        float al = 1.f / (1.f + expf(-s));
        acc.x += h.x * al; acc.y += h.y * al;
    }
    *(float2*)&gps[w][2 * l] = acc;
    __syncthreads();
    if (threadIdx.x < 128) {
        int c = threadIdx.x;
        float s = gps[0][c] + gps[1][c] + gps[2][c] + gps[3][c];
        int b = seg & 63, comm = seg >> 6;
        g12[b * 256 + comm * 128 + c] = s;
    }
}

// ---------------- MLP head ----------------
__global__ void k_mlp(const float* __restrict__ G,
                      const float* __restrict__ Wl1, const float* __restrict__ bl1,
                      const float* __restrict__ Wl2, const float* __restrict__ bl2,
                      const float* __restrict__ Wl3, const float* __restrict__ bl3,
                      float* __restrict__ out) {
    __shared__ float t1[128], t2[64];
    int b = blockIdx.x; int t = threadIdx.x;
    float s = bl1[t];
    for (int k = 0; k < 256; k++) s = fmaf(G[b * 256 + k], Wl1[k * 128 + t], s);
    t1[t] = fmaxf(s, 0.f);
    __syncthreads();
    if (t < 64) {
        float s2 = bl2[t];
        for (int k = 0; k < 128; k++) s2 = fmaf(t1[k], Wl2[k * 64 + t], s2);
        t2[t] = fmaxf(s2, 0.f);
    }
    __syncthreads();
    if (t < 2) {
        float s3 = bl3[t];
        for (int k = 0; k < 64; k++) s3 = fmaf(t2[k], Wl3[k * 2 + t], s3);
        out[b * 2 + t] = s3;
    }
}

// ---------------- launch ----------------
extern "C" void kernel_launch(void* const* d_in, const int* in_sizes, int n_in,
                              void* d_out, int out_size, void* d_ws, size_t ws_size,
                              hipStream_t stream) {
    const float* x       = (const float*)d_in[0];
    const int*   src_all = (const int*)d_in[1];
    const int*   dst_all = (const int*)d_in[2];
    const int*   src_c1  = (const int*)d_in[3];
    const int*   dst_c1  = (const int*)d_in[4];
    const int*   src_c2  = (const int*)d_in[5];
    const int*   dst_c2  = (const int*)d_in[6];
    const float* W1 = (const float*)d_in[7];   const float* b1 = (const float*)d_in[8];
    const float* W2 = (const float*)d_in[9];   const float* b2 = (const float*)d_in[10];
    const float* W3 = (const float*)d_in[11];  const float* b3 = (const float*)d_in[12];
    const float* Wg_att = (const float*)d_in[13];
    const float* Wal = (const float*)d_in[14]; const float* bal = (const float*)d_in[15];
    const float* Wf  = (const float*)d_in[16]; const float* bf  = (const float*)d_in[17];
    const float* Wg_fin = (const float*)d_in[18];
    const float* Wl1 = (const float*)d_in[19]; const float* bl1 = (const float*)d_in[20];
    const float* Wl2 = (const float*)d_in[21]; const float* bl2 = (const float*)d_in[22];
    const float* Wl3 = (const float*)d_in[23]; const float* bl3 = (const float*)d_in[24];
    float* out = (float*)d_out;

    // ---- workspace layout (floats) ----
    float* f = (float*)d_ws;
    size_t o = 0;
    float* XC   = f + o; o += (size_t)NN * 384;
    float* SCR  = f + o; o += (size_t)NN * 128;     // xw*dis; later 2 K-split partials
    float* H    = f + o; o += (size_t)NP2 * 128;
    int* ROWSTART = (int*)(f + o); o += 65552;
    int* CSRC     = (int*)(f + o); o += EALL;
    int* CNTP     = (int*)(f + o); o += NP2;
    float* DIS    = f + o; o += NN;
    // contiguous zero-init region: MSUM | GP | MEANF
    float* MSUM   = f + o; o += 128 * 384;
    float* GP     = f + o; o += 128 * 384;
    float* MEANF  = f + o; o += 128 * 128;
    float* C12    = f + o; o += 128 * 384;
    float* PV     = f + o; o += 64 * 768;
    float* PNORM  = f + o; o += 128;
    float* SC     = f + o; o += 65536;
    int* SEL      = (int*)(f + o); o += NP2;
    int* NMAP     = (int*)(f + o); o += 65536;
    float* DISP   = f + o; o += NP2;
    float* CFIN   = f + o; o += 128 * 128;
    float* G12    = f + o; o += 64 * 256;
    size_t needed_bytes = o * sizeof(float);
    if (ws_size < needed_bytes) return;

    float* XWP0 = SCR;                            // K-half 0 partial
    float* XWP1 = SCR + (size_t)NP2 * 128;        // K-half 1 partial

    // zero the atomic accumulators (one memset: MSUM+GP+MEANF contiguous)
    hipMemsetAsync(MSUM, 0, (128 * 384 + 128 * 384 + 128 * 128) * sizeof(float), stream);

    // ---- full-graph CSR + degrees ----
    k_build_csr<<<128, 256, 0, stream>>>(src_all, dst_all, ROWSTART, CSRC, DIS);

    // ---- 3 GCN layers (mean partials fused into aggregates) ----
    k_gemm_tile<128><<<NN / 128, 256, 0, stream>>>(x, 128, W1, DIS, SCR, NN);
    k_aggregate4<<<NN / 8, 256, 0, stream>>>(SCR, DIS, ROWSTART, CSRC, b1, XC, 0, MSUM);
    k_gemm_tile<128><<<NN / 128, 256, 0, stream>>>(XC + 0, 384, W2, DIS, SCR, NN);
    k_aggregate4<<<NN / 8, 256, 0, stream>>>(SCR, DIS, ROWSTART, CSRC, b2, XC, 128, MSUM);
    k_gemm_tile<128><<<NN / 128, 256, 0, stream>>>(XC + 128, 384, W3, DIS, SCR, NN);
    k_aggregate4<<<NN / 8, 256, 0, stream>>>(SCR, DIS, ROWSTART, CSRC, b3, XC, 256, MSUM);

    // ---- attention pool over communities ----
    k_c12<<<128, 384, 0, stream>>>(MSUM, Wg_att, C12);
    k_attpool1<<<512, 256, 0, stream>>>(XC, C12, GP);
    k_pv<<<64, 768, 0, stream>>>(GP, Wal, bal, PV, PNORM);

    // ---- scores + top-K ----
    k_score<<<65536 / 4, 256, 0, stream>>>(XC, PV, PNORM, SC);
    k_topk<<<128, 256, 0, stream>>>(SC, SEL, NMAP);

    // ---- pooled graph build ----
    k_build_csr_pooled<<<128, 256, 0, stream>>>(src_c1, dst_c1, src_c2, dst_c2,
                                                NMAP, ROWSTART, CNTP, CSRC, DISP);

    // ---- pooled GCN (K-split gathered GEMM + fused-sum CSR aggregate + fused mean) ----
    k_gemm_gather<<<dim3(NP2 / 128, 2), 256, 0, stream>>>(XC, SEL, SC, DISP, Wf, XWP0, XWP1);
    k_aggregate_pooled<<<NP2 / 8, 256, 0, stream>>>(XWP0, XWP1, DISP, ROWSTART, CNTP, CSRC,
                                                    bf, H, MEANF);

    // ---- final attention pool (fused) ----
    k_cfin<<<128, 128, 0, stream>>>(MEANF, Wg_fin, CFIN);
    k_attpool_fin<<<128, 256, 0, stream>>>(H, CFIN, G12);

    // ---- MLP head ----
    k_mlp<<<64, 128, 0, stream>>>(G12, Wl1, bl1, Wl2, bl2, Wl3, bl3, out);
}

// Round 9
// 620.076 us; speedup vs baseline: 1.0936x; 1.0344x over previous
//
#include <hip/hip_runtime.h>
#include <math.h>

// ---------------- constants ----------------
constexpr int BB   = 64;
constexpr int NPB  = 1024;            // nodes per batch graph (N1+N2)
constexpr int NN   = BB * NPB;        // 65536 total nodes
constexpr int EALL = 1048576;         // total edges (both communities)
constexpr int EC   = 524288;          // edges per community
constexpr int EPG  = 8192;            // edges per (batch,community) group == N1*DEG
constexpr int KTOP = 256;             // K1 == K2
constexpr int NP   = BB * KTOP;       // 16384 pooled nodes per community
constexpr int NP2  = 2 * NP;          // 32768 pooled nodes total

typedef __attribute__((ext_vector_type(8))) short bf16x8;
typedef __attribute__((ext_vector_type(4))) unsigned short us4;
typedef __attribute__((ext_vector_type(8))) unsigned short us8;
typedef __attribute__((ext_vector_type(4))) float f32x4;

__device__ __forceinline__ unsigned short f2bf(float f) {      // truncation split
    return (unsigned short)(__float_as_uint(f) >> 16);
}
__device__ __forceinline__ float bf2f(unsigned short h) {
    return __uint_as_float(((unsigned)h) << 16);
}

// physical quad swizzle for Ws (fp32 GEMM): bijective on 0..31; reads/writes 2-way (free)
__device__ __forceinline__ int pq(int q) { return q ^ (q >> 3); }

// ---------------- full-graph CSR build: per-group LDS counting sort ----------------
__global__ __launch_bounds__(256) void k_build_csr(const int* __restrict__ src_all,
                                                   const int* __restrict__ dst_all,
                                                   int* __restrict__ rowstart,
                                                   int* __restrict__ csrc,
                                                   float* __restrict__ dis) {
    __shared__ int cnt[512];
    __shared__ int rs[512];
    __shared__ int wsum[4];
    __shared__ int stage[EPG];
    const int g = blockIdx.x;
    const int b = g >> 1, c = g & 1;
    const int ebase  = c * EC + b * EPG;
    const int region = g * EPG;
    const int nbase  = g * 512;
    const int t = threadIdx.x;
    const int lane = t & 63, w = t >> 6;

    cnt[t] = 0; cnt[t + 256] = 0;
    __syncthreads();
    for (int i = 0; i < 32; i++) {
        int d = dst_all[ebase + t + 256 * i] & 511;
        atomicAdd(&cnt[d], 1);
    }
    __syncthreads();
    int v0 = cnt[2 * t], v1 = cnt[2 * t + 1];
    int p = v0 + v1;
    int incl = p;
    for (int off = 1; off < 64; off <<= 1) {
        int u = __shfl_up(incl, off);
        if (lane >= off) incl += u;
    }
    if (lane == 63) wsum[w] = incl;
    __syncthreads();
    int base = 0;
    for (int i = 0; i < w; i++) base += wsum[i];
    int excl = base + incl - p;
    rs[2 * t] = excl;
    rs[2 * t + 1] = excl + v0;
    rowstart[nbase + 2 * t]     = region + excl;
    rowstart[nbase + 2 * t + 1] = region + excl + v0;
    dis[nbase + 2 * t]     = 1.0f / sqrtf((float)v0 + 1.0f);
    dis[nbase + 2 * t + 1] = 1.0f / sqrtf((float)v1 + 1.0f);
    if (g == 127 && t == 0) rowstart[NN] = EALL;
    __syncthreads();
    for (int i = 0; i < 32; i++) {
        int e = ebase + t + 256 * i;
        int d = dst_all[e] & 511;
        int pp = atomicAdd(&rs[d], 1);
        stage[pp] = src_all[e];
    }
    __syncthreads();
    for (int i = 0; i < 32; i++)
        csrc[region + t + 256 * i] = stage[t + 256 * i];
}

// ---------------- pooled CSR build ----------------
__global__ __launch_bounds__(256) void k_build_csr_pooled(const int* __restrict__ s1,
                                                          const int* __restrict__ d1,
                                                          const int* __restrict__ s2,
                                                          const int* __restrict__ d2,
                                                          const int* __restrict__ nmap,
                                                          int* __restrict__ rowstart,
                                                          int* __restrict__ cntp,
                                                          int* __restrict__ csre,
                                                          float* __restrict__ disp) {
    __shared__ int cnt[256];
    __shared__ int rs[256];
    __shared__ int wsum[4];
    __shared__ int stage[EPG];
    const int g = blockIdx.x;
    const int c = g >> 6, b = g & 63;
    const int* ss = c ? s2 : s1;
    const int* dd = c ? d2 : d1;
    const int* nm = nmap + c * 32768;
    const int ebase  = b * EPG;
    const int region = g * EPG;
    const int nbase  = g * 256;
    const int t = threadIdx.x;
    const int lane = t & 63, w = t >> 6;

    cnt[t] = 0;
    __syncthreads();
    for (int i = 0; i < 32; i++) {
        int e = ebase + t + 256 * i;
        int r = nm[ss[e]], cc = nm[dd[e]];
        if (r >= 0 && cc >= 0) atomicAdd(&cnt[cc & 255], 1);
    }
    __syncthreads();
    int v = cnt[t];
    int incl = v;
    for (int off = 1; off < 64; off <<= 1) {
        int u = __shfl_up(incl, off);
        if (lane >= off) incl += u;
    }
    if (lane == 63) wsum[w] = incl;
    __syncthreads();
    int base = 0;
    for (int i = 0; i < w; i++) base += wsum[i];
    int excl = base + incl - v;
    rs[t] = excl;
    rowstart[nbase + t] = region + excl;
    cntp[nbase + t] = v;
    disp[nbase + t] = 1.0f / sqrtf((float)v + 1.0f);
    __syncthreads();
    for (int i = 0; i < 32; i++) {
        int e = ebase + t + 256 * i;
        int r = nm[ss[e]], cc = nm[dd[e]];
        if (r >= 0 && cc >= 0) {
            int pp = atomicAdd(&rs[cc & 255], 1);
            stage[pp] = r;
        }
    }
    __syncthreads();
    for (int i = 0; i < 32; i++)
        csre[region + t + 256 * i] = stage[t + 256 * i];
}

// ---------------- fp32 GEMM (layers): C[M x 128] = A[M x KDIM] @ W, row-scaled ----------------
template <int KDIM>
__global__ __launch_bounds__(256) void k_gemm_tile(const float* __restrict__ A, int lda,
                                                   const float* __restrict__ W,
                                                   const float* __restrict__ rowscale,
                                                   float* __restrict__ C, int M) {
    __shared__ float As[32][132];
    __shared__ float Ws[32 * 128];
    const int tid  = threadIdx.x;
    const int c0 = (tid & 15) * 8;
    const int r0 = (tid >> 4) * 8;
    const int row0 = blockIdx.x * 128;
    const int arow = tid >> 1;
    const int aq   = tid & 1;
    const float* Ap = A + (size_t)(row0 + arow) * lda;
    const int pq0 = pq(c0 >> 2) * 4;
    const int pq1 = pq((c0 >> 2) + 1) * 4;

    float acc[8][8];
#pragma unroll
    for (int i = 0; i < 8; i++)
#pragma unroll
        for (int j = 0; j < 8; j++) acc[i][j] = 0.f;

    float4 areg[4], wreg[4];
#pragma unroll
    for (int qq = 0; qq < 4; qq++)
        areg[qq] = *(const float4*)(Ap + (aq + 2 * qq) * 4);
#pragma unroll
    for (int q = 0; q < 4; q++) {
        int f = tid + 256 * q;
        wreg[q] = *(const float4*)(W + (size_t)(f >> 5) * 128 + (f & 31) * 4);
    }

    constexpr int NT = KDIM / 32;
    for (int t = 0; t < NT; t++) {
#pragma unroll
        for (int qq = 0; qq < 4; qq++) {
            int kk = (aq + 2 * qq) * 4;
            As[kk + 0][arow] = areg[qq].x;
            As[kk + 1][arow] = areg[qq].y;
            As[kk + 2][arow] = areg[qq].z;
            As[kk + 3][arow] = areg[qq].w;
        }
#pragma unroll
        for (int q = 0; q < 4; q++) {
            int f = tid + 256 * q;
            *(float4*)&Ws[(f >> 5) * 128 + pq(f & 31) * 4] = wreg[q];
        }
        __syncthreads();
        if (t + 1 < NT) {
            int k0 = (t + 1) * 32;
#pragma unroll
            for (int qq = 0; qq < 4; qq++)
                areg[qq] = *(const float4*)(Ap + k0 + (aq + 2 * qq) * 4);
#pragma unroll
            for (int q = 0; q < 4; q++) {
                int f = tid + 256 * q;
                wreg[q] = *(const float4*)(W + (size_t)(k0 + (f >> 5)) * 128 + (f & 31) * 4);
            }
        }
#pragma unroll 2
        for (int kk = 0; kk < 32; kk++) {
            float4 a0 = *(const float4*)&As[kk][r0];
            float4 a1 = *(const float4*)&As[kk][r0 + 4];
            float4 b0 = *(const float4*)&Ws[kk * 128 + pq0];
            float4 b1 = *(const float4*)&Ws[kk * 128 + pq1];
            float a[8] = {a0.x, a0.y, a0.z, a0.w, a1.x, a1.y, a1.z, a1.w};
            float b[8] = {b0.x, b0.y, b0.z, b0.w, b1.x, b1.y, b1.z, b1.w};
#pragma unroll
            for (int i = 0; i < 8; i++)
#pragma unroll
                for (int j = 0; j < 8; j++)
                    acc[i][j] = fmaf(a[i], b[j], acc[i][j]);
        }
        if (t + 1 < NT) __syncthreads();
    }
#pragma unroll
    for (int i = 0; i < 8; i++) {
        int row = row0 + r0 + i;
        if (row < M) {
            float sc = rowscale[row];
            float4 o0 = {acc[i][0]*sc, acc[i][1]*sc, acc[i][2]*sc, acc[i][3]*sc};
            float4 o1 = {acc[i][4]*sc, acc[i][5]*sc, acc[i][6]*sc, acc[i][7]*sc};
            *(float4*)(C + (size_t)row * 128 + c0) = o0;
            *(float4*)(C + (size_t)row * 128 + c0 + 4) = o1;
        }
    }
}

// ---------------- Wf prep: transpose + bf16 hi/lo split ([n=128][k=384]) ----------------
__global__ void k_prep_wf(const float* __restrict__ Wf,
                          unsigned short* __restrict__ hi, unsigned short* __restrict__ lo) {
    int g = blockIdx.x * 256 + threadIdx.x;   // 0..49151
    int n = g / 384, k = g - n * 384;
    float v = Wf[k * 128 + n];
    unsigned short h = f2bf(v);
    hi[g] = h;
    lo[g] = f2bf(v - bf2f(h));
}

// ---------------- pooled gathered GEMM: MFMA bf16x3 (post-selection, continuous path) ----
__global__ __launch_bounds__(256) void k_gemm_gather_mfma(const float* __restrict__ XC,
                                                          const int* __restrict__ sel,
                                                          const float* __restrict__ SC,
                                                          const float* __restrict__ rowscale,
                                                          const unsigned short* __restrict__ WH,
                                                          const unsigned short* __restrict__ WL,
                                                          float* __restrict__ C) {
    __shared__ unsigned short Ah[128][40], Al[128][40], Wh[128][40], Wl[128][40];
    const int tid  = threadIdx.x;
    const int wid  = tid >> 6, lane = tid & 63;
    const int quad = lane >> 4, m15 = lane & 15;
    const int row0 = blockIdx.x * 128;
    const int arow = tid >> 1, aq = tid & 1;
    const int wn   = tid >> 1, wh2 = tid & 1;

    int n = row0 + arow;
    int comm = n >= NP;
    int nl = n - (comm ? NP : 0);
    int b = nl >> 8;
    int old = sel[n];
    const float* Ap = XC + (size_t)(b * NPB + comm * 512 + old) * 384;
    float scv = SC[comm * 32768 + b * 512 + old];
    float sg = 1.f / (1.f + expf(-scv));

    f32x4 acc[2][8];
#pragma unroll
    for (int i = 0; i < 2; i++)
#pragma unroll
        for (int j = 0; j < 8; j++) acc[i][j] = (f32x4){0.f, 0.f, 0.f, 0.f};

    float4 areg[4];
#pragma unroll
    for (int qq = 0; qq < 4; qq++)
        areg[qq] = *(const float4*)(Ap + (aq + 2 * qq) * 4);

    constexpr int NT = 12;
    for (int t = 0; t < NT; t++) {
        if (t) __syncthreads();
#pragma unroll
        for (int qq = 0; qq < 4; qq++) {
            int k = (aq + 2 * qq) * 4;
            float4 v = areg[qq];
            v.x *= sg; v.y *= sg; v.z *= sg; v.w *= sg;
            us4 h, l;
            h.x = f2bf(v.x); l.x = f2bf(v.x - bf2f(h.x));
            h.y = f2bf(v.y); l.y = f2bf(v.y - bf2f(h.y));
            h.z = f2bf(v.z); l.z = f2bf(v.z - bf2f(h.z));
            h.w = f2bf(v.w); l.w = f2bf(v.w - bf2f(h.w));
            *(us4*)&Ah[arow][k] = h;
            *(us4*)&Al[arow][k] = l;
        }
        int k0 = t * 32;
#pragma unroll
        for (int c = 0; c < 2; c++) {
            int kc = 8 * (wh2 + 2 * c);
            *(us8*)&Wh[wn][kc] = *(const us8*)&WH[(size_t)wn * 384 + k0 + kc];
            *(us8*)&Wl[wn][kc] = *(const us8*)&WL[(size_t)wn * 384 + k0 + kc];
        }
        __syncthreads();
        if (t + 1 < NT) {
            int kn = (t + 1) * 32;
#pragma unroll
            for (int qq = 0; qq < 4; qq++)
                areg[qq] = *(const float4*)(Ap + kn + (aq + 2 * qq) * 4);
        }
        bf16x8 ah[2], al2[2];
#pragma unroll
        for (int rt = 0; rt < 2; rt++) {
            int r = wid * 32 + rt * 16 + m15;
            ah[rt]  = *(const bf16x8*)&Ah[r][quad * 8];
            al2[rt] = *(const bf16x8*)&Al[r][quad * 8];
        }
#pragma unroll
        for (int ct = 0; ct < 8; ct++) {
            int nn = ct * 16 + m15;
            bf16x8 bh = *(const bf16x8*)&Wh[nn][quad * 8];
            bf16x8 bl = *(const bf16x8*)&Wl[nn][quad * 8];
#pragma unroll
            for (int rt = 0; rt < 2; rt++) {
                acc[rt][ct] = __builtin_amdgcn_mfma_f32_16x16x32_bf16(ah[rt], bh, acc[rt][ct], 0, 0, 0);
                acc[rt][ct] = __builtin_amdgcn_mfma_f32_16x16x32_bf16(al2[rt], bh, acc[rt][ct], 0, 0, 0);
                acc[rt][ct] = __builtin_amdgcn_mfma_f32_16x16x32_bf16(ah[rt], bl, acc[rt][ct], 0, 0, 0);
            }
        }
    }
    // C/D layout: col = lane&15, row = quad*4 + reg
#pragma unroll
    for (int rt = 0; rt < 2; rt++)
#pragma unroll
        for (int reg = 0; reg < 4; reg++) {
            int row = row0 + wid * 32 + rt * 16 + quad * 4 + reg;
            float sc = rowscale[row];
#pragma unroll
            for (int ct = 0; ct < 8; ct++)
                C[(size_t)row * 128 + ct * 16 + m15] = acc[rt][ct][reg] * sc;
        }
}

// ---------------- GCN aggregation + deterministic column-mean partial slots ----------------
__global__ void k_aggregate4(const float* __restrict__ xwsc, const float* __restrict__ dis,
                             const int* __restrict__ rowstart, const int* __restrict__ csrc,
                             const float* __restrict__ bias, float* __restrict__ XC, int colbase,
                             float* __restrict__ mpart) {
    __shared__ float redf[8][128];
    int xcd  = blockIdx.x & 7;
    int slot = blockIdx.x >> 3;            // 0..1023
    int g    = ((slot >> 6) << 3) | xcd;   // 0..127
    int bslot = slot & 63;                 // within-group block slot (deterministic)
    int node = g * 512 + bslot * 8 + (threadIdx.x >> 5);
    int l    = threadIdx.x & 31;
    const float4* xw4 = (const float4*)xwsc;
    float4 acc = xw4[(size_t)node * 32 + l];
    int e0 = rowstart[node], e1 = rowstart[node + 1];
    for (int e = e0; e < e1; e++) {
        int s = csrc[e];
        float4 u = xw4[(size_t)s * 32 + l];
        acc.x += u.x; acc.y += u.y; acc.z += u.z; acc.w += u.w;
    }
    float di = dis[node];
    float4 b4 = ((const float4*)bias)[l];
    acc.x = fmaxf(acc.x * di + b4.x, 0.f);
    acc.y = fmaxf(acc.y * di + b4.y, 0.f);
    acc.z = fmaxf(acc.z * di + b4.z, 0.f);
    acc.w = fmaxf(acc.w * di + b4.w, 0.f);
    *(float4*)(XC + (size_t)node * 384 + colbase + l * 4) = acc;
    *(float4*)&redf[threadIdx.x >> 5][l * 4] = acc;
    __syncthreads();
    if (threadIdx.x < 128) {
        int c = threadIdx.x;
        float s = 0.f;
#pragma unroll
        for (int r = 0; r < 8; r++) s += redf[r][c];
        mpart[((size_t)(g * 64 + bslot)) * 384 + colbase + c] = s;   // no atomics
    }
}

// pooled variant: fused H-mean partials (atomic OK — continuous path only)
__global__ void k_aggregate_pooled(const float* __restrict__ xw, const float* __restrict__ disp,
                                   const int* __restrict__ rowstart, const int* __restrict__ cntp,
                                   const int* __restrict__ csre,
                                   const float* __restrict__ bias, float* __restrict__ H,
                                   float* __restrict__ meansum) {
    __shared__ float redf[8][128];
    int xcd  = blockIdx.x & 7;
    int slot = blockIdx.x >> 3;            // 0..511
    int g    = ((slot >> 5) << 3) | xcd;   // 0..127
    int node = g * 256 + (slot & 31) * 8 + (threadIdx.x >> 5);
    int l    = threadIdx.x & 31;
    const float4* x4 = (const float4*)xw;
    float4 acc = x4[(size_t)node * 32 + l];
    int e0 = rowstart[node], n = cntp[node];
    for (int i = 0; i < n; i++) {
        int r = csre[e0 + i];
        float4 u = x4[(size_t)r * 32 + l];
        acc.x += u.x; acc.y += u.y; acc.z += u.z; acc.w += u.w;
    }
    float di = disp[node];
    float4 b4 = ((const float4*)bias)[l];
    acc.x = fmaxf(acc.x * di + b4.x, 0.f);
    acc.y = fmaxf(acc.y * di + b4.y, 0.f);
    acc.z = fmaxf(acc.z * di + b4.z, 0.f);
    acc.w = fmaxf(acc.w * di + b4.w, 0.f);
    *(float4*)(H + (size_t)node * 128 + l * 4) = acc;
    *(float4*)&redf[threadIdx.x >> 5][l * 4] = acc;
    __syncthreads();
    if (threadIdx.x < 128) {
        int c = threadIdx.x;
        float s = 0.f;
#pragma unroll
        for (int r = 0; r < 8; r++) s += redf[r][c];
        atomicAdd(&meansum[g * 128 + c], s);
    }
}

// ---------------- attention pool stage 1 ----------------
// c12 from deterministic mean partials (fixed-order 64-slot sum)
__global__ void k_c12(const float* __restrict__ mpart, const float* __restrict__ Wg,
                      float* __restrict__ c12) {
    __shared__ float ms[384];
    int seg = blockIdx.x; int c = threadIdx.x;   // 384 threads
    int g = ((seg & 63) << 1) | (seg >> 6);
    float s0 = 0.f;
    for (int s2 = 0; s2 < 64; s2++)
        s0 += mpart[((size_t)(g * 64 + s2)) * 384 + c];
    ms[c] = s0 * (1.0f / 512.0f);
    __syncthreads();
    float s = 0.f;
    for (int k = 0; k < 384; k++) s = fmaf(ms[k], Wg[(size_t)k * 384 + c], s);
    c12[seg * 384 + c] = tanhf(s);
}

// fused alpha+gp: each of 4 blocks per group writes a deterministic partial slot
__global__ __launch_bounds__(256) void k_attpool1(const float* __restrict__ XC,
                                                  const float* __restrict__ C12,
                                                  float* __restrict__ GPP) {
    __shared__ float gps[4][384];
    int blk = blockIdx.x;              // 0..511 (4 per group)
    int gc = blk >> 2, q = blk & 3;
    int seg = ((gc & 1) << 6) | (gc >> 1);
    int w = threadIdx.x >> 6, l = threadIdx.x & 63;
    const float* c12r = C12 + seg * 384;
    float4 cr0 = *(const float4*)(c12r + 4 * l);
    float4 cr1 = (l < 32) ? *(const float4*)(c12r + 256 + 4 * l) : float4{0.f,0.f,0.f,0.f};
    float4 a0 = {0.f,0.f,0.f,0.f}, a1 = {0.f,0.f,0.f,0.f};
    int base = gc * 512 + q * 128 + w * 32;
    for (int it = 0; it < 32; it++) {
        const float* xr = XC + (size_t)(base + it) * 384;
        float4 v0 = *(const float4*)(xr + 4 * l);
        float4 v1 = (l < 32) ? *(const float4*)(xr + 256 + 4 * l) : float4{0.f,0.f,0.f,0.f};
        float s = v0.x*cr0.x + v0.y*cr0.y + v0.z*cr0.z + v0.w*cr0.w
                + v1.x*cr1.x + v1.y*cr1.y + v1.z*cr1.z + v1.w*cr1.w;
        for (int off = 32; off; off >>= 1) s += __shfl_xor(s, off);
        float al = 1.f / (1.f + expf(-s));
        a0.x += v0.x*al; a0.y += v0.y*al; a0.z += v0.z*al; a0.w += v0.w*al;
        a1.x += v1.x*al; a1.y += v1.y*al; a1.z += v1.z*al; a1.w += v1.w*al;
    }
    *(float4*)&gps[w][4 * l] = a0;
    if (l < 32) *(float4*)&gps[w][256 + 4 * l] = a1;
    __syncthreads();
    for (int c = threadIdx.x; c < 384; c += 256) {
        float s = gps[0][c] + gps[1][c] + gps[2][c] + gps[3][c];
        GPP[(size_t)(seg * 4 + q) * 384 + c] = s;      // deterministic slot write
    }
}

// pv + fused pnorm; reduces the 4 GP partial slots in fixed order
__global__ void k_pv(const float* __restrict__ GPP, const float* __restrict__ Wal,
                     const float* __restrict__ bal, float* __restrict__ pv,
                     float* __restrict__ pnorm) {
    __shared__ float gpls[768];
    __shared__ float red[768];
    int row = blockIdx.x;               // 0..63
    int c   = threadIdx.x;              // 0..767
    {
        int seg = (c < 384) ? row : (64 + row);
        int k   = (c < 384) ? c : (c - 384);
        float v = GPP[(size_t)(seg * 4 + 0) * 384 + k] + GPP[(size_t)(seg * 4 + 1) * 384 + k]
                + GPP[(size_t)(seg * 4 + 2) * 384 + k] + GPP[(size_t)(seg * 4 + 3) * 384 + k];
        gpls[c] = v;
    }
    __syncthreads();
    float s = bal[c];
    for (int k = 0; k < 768; k++) s = fmaf(gpls[k], Wal[(size_t)k * 768 + c], s);
    pv[row * 768 + c] = s;
    red[c] = s * s;
    __syncthreads();
    int wv = c >> 6, ln = c & 63;
    if (wv < 2) {
        float s2 = 0.f;
#pragma unroll
        for (int i = 0; i < 6; i++) s2 += red[wv * 384 + ln + 64 * i];
        for (int off = 32; off; off >>= 1) s2 += __shfl_down(s2, off);
        if (ln == 0) pnorm[wv * 64 + row] = sqrtf(s2);
    }
}

// ---------------- scores (both communities) + per-batch top-K ----------------
__global__ void k_score(const float* __restrict__ XC, const float* __restrict__ pv,
                        const float* __restrict__ pnorm, float* __restrict__ sc) {
    int nl2 = blockIdx.x * 4 + (threadIdx.x >> 6);   // 0..65535
    int lane = threadIdx.x & 63;
    int comm = nl2 >> 15;
    int nl = nl2 & 32767;
    int b = nl >> 9; int i = nl & 511;
    const float* xr = XC + (size_t)(b * NPB + comm * 512 + i) * 384;
    const float* pr = pv + b * 768 + comm * 384;
    float4 x0 = *(const float4*)(xr + 4 * lane);
    float4 p0 = *(const float4*)(pr + 4 * lane);
    float s = x0.x*p0.x + x0.y*p0.y + x0.z*p0.z + x0.w*p0.w;
    if (lane < 32) {
        float4 x1 = *(const float4*)(xr + 256 + 4 * lane);
        float4 p1 = *(const float4*)(pr + 256 + 4 * lane);
        s += x1.x*p1.x + x1.y*p1.y + x1.z*p1.z + x1.w*p1.w;
    }
    for (int off = 32; off; off >>= 1) s += __shfl_down(s, off);
    if (lane == 0) sc[comm * 32768 + nl] = s / pnorm[comm * 64 + b];
}

__global__ void k_topk(const float* __restrict__ sc, int* __restrict__ sel, int* __restrict__ nmap) {
    __shared__ float sv[512];
    __shared__ int   si[512];
    int blk = blockIdx.x;               // 0..127 = comm*64 + b
    int t = threadIdx.x;                // 0..255
    sv[t] = sc[blk * 512 + t];             si[t] = t;
    sv[t + 256] = sc[blk * 512 + t + 256]; si[t + 256] = t + 256;
    __syncthreads();
    for (int k2 = 2; k2 <= 512; k2 <<= 1) {
        for (int j = k2 >> 1; j > 0; j >>= 1) {
            for (int i = t; i < 512; i += 256) {
                int l = i ^ j;
                if (l > i) {
                    bool desc = ((i & k2) == 0);
                    float a = sv[i], bb2 = sv[l];
                    bool sw = desc ? (a < bb2) : (a > bb2);
                    if (sw) {
                        sv[i] = bb2; sv[l] = a;
                        int tmp = si[i]; si[i] = si[l]; si[l] = tmp;
                    }
                }
            }
            __syncthreads();
        }
    }
    sel[blk * 256 + t] = si[t];
    nmap[blk * 512 + si[t]] = blk * 256 + t;
    nmap[blk * 512 + si[t + 256]] = -1;
}

// ---------------- final attention pool (fused alpha + weighted segment sum) ----------------
__global__ void k_cfin(const float* __restrict__ meansum, const float* __restrict__ Wg,
                       float* __restrict__ cf) {
    __shared__ float ms[128];
    int b = blockIdx.x; int c = threadIdx.x;
    ms[c] = meansum[b * 128 + c] * (1.0f / 256.0f);
    __syncthreads();
    float s = 0.f;
    for (int k = 0; k < 128; k++) s = fmaf(ms[k], Wg[k * 128 + c], s);
    cf[b * 128 + c] = tanhf(s);
}

__global__ __launch_bounds__(256) void k_attpool_fin(const float* __restrict__ H,
                                                     const float* __restrict__ cf,
                                                     float* __restrict__ g12) {
    __shared__ float gps[4][128];
    int seg = blockIdx.x;               // 0..127 = comm*64 + b
    int w = threadIdx.x >> 6, l = threadIdx.x & 63;
    const float2 cfl = *(const float2*)(cf + seg * 128 + 2 * l);
    float2 acc = {0.f, 0.f};
    int base = seg * 256 + w * 64;
    for (int it = 0; it < 64; it++) {
        const float2 h = *(const float2*)(H + (size_t)(base + it) * 128 + 2 * l);
        float s = h.x * cfl.x + h.y * cfl.y;
        for (int off = 32; off; off >>= 1) s += __shfl_xor(s, off);
        float al = 1.f / (1.f + expf(-s));
        acc.x += h.x * al; acc.y += h.y * al;
    }
    *(float2*)&gps[w][2 * l] = acc;
    __syncthreads();
    if (threadIdx.x < 128) {
        int c = threadIdx.x;
        float s = gps[0][c] + gps[1][c] + gps[2][c] + gps[3][c];
        int b = seg & 63, comm = seg >> 6;
        g12[b * 256 + comm * 128 + c] = s;
    }
}

// ---------------- MLP head ----------------
__global__ void k_mlp(const float* __restrict__ G,
                      const float* __restrict__ Wl1, const float* __restrict__ bl1,
                      const float* __restrict__ Wl2, const float* __restrict__ bl2,
                      const float* __restrict__ Wl3, const float* __restrict__ bl3,
                      float* __restrict__ out) {
    __shared__ float t1[128], t2[64];
    int b = blockIdx.x; int t = threadIdx.x;
    float s = bl1[t];
    for (int k = 0; k < 256; k++) s = fmaf(G[b * 256 + k], Wl1[k * 128 + t], s);
    t1[t] = fmaxf(s, 0.f);
    __syncthreads();
    if (t < 64) {
        float s2 = bl2[t];
        for (int k = 0; k < 128; k++) s2 = fmaf(t1[k], Wl2[k * 64 + t], s2);
        t2[t] = fmaxf(s2, 0.f);
    }
    __syncthreads();
    if (t < 2) {
        float s3 = bl3[t];
        for (int k = 0; k < 64; k++) s3 = fmaf(t2[k], Wl3[k * 2 + t], s3);
        out[b * 2 + t] = s3;
    }
}

// ---------------- launch ----------------
extern "C" void kernel_launch(void* const* d_in, const int* in_sizes, int n_in,
                              void* d_out, int out_size, void* d_ws, size_t ws_size,
                              hipStream_t stream) {
    const float* x       = (const float*)d_in[0];
    const int*   src_all = (const int*)d_in[1];
    const int*   dst_all = (const int*)d_in[2];
    const int*   src_c1  = (const int*)d_in[3];
    const int*   dst_c1  = (const int*)d_in[4];
    const int*   src_c2  = (const int*)d_in[5];
    const int*   dst_c2  = (const int*)d_in[6];
    const float* W1 = (const float*)d_in[7];   const float* b1 = (const float*)d_in[8];
    const float* W2 = (const float*)d_in[9];   const float* b2 = (const float*)d_in[10];
    const float* W3 = (const float*)d_in[11];  const float* b3 = (const float*)d_in[12];
    const float* Wg_att = (const float*)d_in[13];
    const float* Wal = (const float*)d_in[14]; const float* bal = (const float*)d_in[15];
    const float* Wf  = (const float*)d_in[16]; const float* bf  = (const float*)d_in[17];
    const float* Wg_fin = (const float*)d_in[18];
    const float* Wl1 = (const float*)d_in[19]; const float* bl1 = (const float*)d_in[20];
    const float* Wl2 = (const float*)d_in[21]; const float* bl2 = (const float*)d_in[22];
    const float* Wl3 = (const float*)d_in[23]; const float* bl3 = (const float*)d_in[24];
    float* out = (float*)d_out;

    // ---- workspace layout (floats) ----
    float* f = (float*)d_ws;
    size_t o = 0;
    float* XC   = f + o; o += (size_t)NN * 384;
    float* SCR  = f + o; o += (size_t)NN * 128;     // xw*dis; later XWP (NP2 x 128)
    float* H    = f + o; o += (size_t)NP2 * 128;    // pooled conv out; earlier aliased as MPART
    int* ROWSTART = (int*)(f + o); o += 65552;
    int* CSRC     = (int*)(f + o); o += EALL;
    int* CNTP     = (int*)(f + o); o += NP2;
    float* DIS    = f + o; o += NN;
    float* GPP    = f + o; o += 512 * 384;          // GP partial slots (deterministic)
    float* MEANF  = f + o; o += 128 * 128;          // atomic (continuous path)
    float* C12    = f + o; o += 128 * 384;
    float* PV     = f + o; o += 64 * 768;
    float* PNORM  = f + o; o += 128;
    float* SC     = f + o; o += 65536;
    int* SEL      = (int*)(f + o); o += NP2;
    int* NMAP     = (int*)(f + o); o += 65536;
    float* DISP   = f + o; o += NP2;
    float* CFIN   = f + o; o += 128 * 128;
    float* G12    = f + o; o += 64 * 256;
    unsigned short* WBH = (unsigned short*)(f + o); o += 24576;   // 49152 bf16
    unsigned short* WBL = (unsigned short*)(f + o); o += 24576;
    size_t needed_bytes = o * sizeof(float);
    if (ws_size < needed_bytes) return;

    float* MPART = H;                   // 128*64*384 = 3.1M floats <= H (4.2M) — H written later
    float* XWP   = SCR;                 // pooled GEMM output (NP2 x 128), reuses SCR

    // zero the remaining atomic accumulator (MEANF only)
    hipMemsetAsync(MEANF, 0, 128 * 128 * sizeof(float), stream);

    // ---- Wf prep (transpose + bf16 hi/lo) ----
    k_prep_wf<<<192, 256, 0, stream>>>(Wf, WBH, WBL);

    // ---- full-graph CSR + degrees ----
    k_build_csr<<<128, 256, 0, stream>>>(src_all, dst_all, ROWSTART, CSRC, DIS);

    // ---- 3 GCN layers (fp32 GEMM keeps the selection path bit-stable) ----
    k_gemm_tile<128><<<NN / 128, 256, 0, stream>>>(x, 128, W1, DIS, SCR, NN);
    k_aggregate4<<<NN / 8, 256, 0, stream>>>(SCR, DIS, ROWSTART, CSRC, b1, XC, 0, MPART);
    k_gemm_tile<128><<<NN / 128, 256, 0, stream>>>(XC + 0, 384, W2, DIS, SCR, NN);
    k_aggregate4<<<NN / 8, 256, 0, stream>>>(SCR, DIS, ROWSTART, CSRC, b2, XC, 128, MPART);
    k_gemm_tile<128><<<NN / 128, 256, 0, stream>>>(XC + 128, 384, W3, DIS, SCR, NN);
    k_aggregate4<<<NN / 8, 256, 0, stream>>>(SCR, DIS, ROWSTART, CSRC, b3, XC, 256, MPART);

    // ---- attention pool over communities (deterministic reductions) ----
    k_c12<<<128, 384, 0, stream>>>(MPART, Wg_att, C12);
    k_attpool1<<<512, 256, 0, stream>>>(XC, C12, GPP);
    k_pv<<<64, 768, 0, stream>>>(GPP, Wal, bal, PV, PNORM);

    // ---- scores + top-K ----
    k_score<<<65536 / 4, 256, 0, stream>>>(XC, PV, PNORM, SC);
    k_topk<<<128, 256, 0, stream>>>(SC, SEL, NMAP);

    // ---- pooled graph build ----
    k_build_csr_pooled<<<128, 256, 0, stream>>>(src_c1, dst_c1, src_c2, dst_c2,
                                                NMAP, ROWSTART, CNTP, CSRC, DISP);

    // ---- pooled GCN (MFMA bf16x3 gathered GEMM — post-selection, continuous path) ----
    k_gemm_gather_mfma<<<NP2 / 128, 256, 0, stream>>>(XC, SEL, SC, DISP, WBH, WBL, XWP);
    k_aggregate_pooled<<<NP2 / 8, 256, 0, stream>>>(XWP, DISP, ROWSTART, CNTP, CSRC,
                                                    bf, H, MEANF);

    // ---- final attention pool (fused) ----
    k_cfin<<<128, 128, 0, stream>>>(MEANF, Wg_fin, CFIN);
    k_attpool_fin<<<128, 256, 0, stream>>>(H, CFIN, G12);

    // ---- MLP head ----
    k_mlp<<<64, 128, 0, stream>>>(G12, Wl1, bl1, Wl2, bl2, Wl3, bl3, out);
}

// Round 10
// 575.263 us; speedup vs baseline: 1.1788x; 1.0779x over previous
//
#include <hip/hip_runtime.h>
#include <math.h>

// ---------------- constants ----------------
constexpr int BB   = 64;
constexpr int NPB  = 1024;            // nodes per batch graph (N1+N2)
constexpr int NN   = BB * NPB;        // 65536 total nodes
constexpr int EALL = 1048576;         // total edges (both communities)
constexpr int EC   = 524288;          // edges per community
constexpr int EPG  = 8192;            // edges per (batch,community) group == N1*DEG
constexpr int KTOP = 256;             // K1 == K2
constexpr int NP   = BB * KTOP;       // 16384 pooled nodes per community
constexpr int NP2  = 2 * NP;          // 32768 pooled nodes total

typedef __attribute__((ext_vector_type(8))) short bf16x8;
typedef __attribute__((ext_vector_type(4))) unsigned short us4;
typedef __attribute__((ext_vector_type(8))) unsigned short us8;
typedef __attribute__((ext_vector_type(4))) float f32x4;

__device__ __forceinline__ unsigned short f2bf(float f) {      // truncation split
    return (unsigned short)(__float_as_uint(f) >> 16);
}
__device__ __forceinline__ float bf2f(unsigned short h) {
    return __uint_as_float(((unsigned)h) << 16);
}

// physical quad swizzle for Ws (fp32 GEMM): bijective on 0..31; reads/writes 2-way (free)
__device__ __forceinline__ int pq(int q) { return q ^ (q >> 3); }

// ---------------- full-graph CSR build: per-group LDS counting sort ----------------
__global__ __launch_bounds__(256) void k_build_csr(const int* __restrict__ src_all,
                                                   const int* __restrict__ dst_all,
                                                   int* __restrict__ rowstart,
                                                   int* __restrict__ csrc,
                                                   float* __restrict__ dis) {
    __shared__ int cnt[512];
    __shared__ int rs[512];
    __shared__ int wsum[4];
    __shared__ int stage[EPG];
    const int g = blockIdx.x;
    const int b = g >> 1, c = g & 1;
    const int ebase  = c * EC + b * EPG;
    const int region = g * EPG;
    const int nbase  = g * 512;
    const int t = threadIdx.x;
    const int lane = t & 63, w = t >> 6;

    cnt[t] = 0; cnt[t + 256] = 0;
    __syncthreads();
    for (int i = 0; i < 32; i++) {
        int d = dst_all[ebase + t + 256 * i] & 511;
        atomicAdd(&cnt[d], 1);
    }
    __syncthreads();
    int v0 = cnt[2 * t], v1 = cnt[2 * t + 1];
    int p = v0 + v1;
    int incl = p;
    for (int off = 1; off < 64; off <<= 1) {
        int u = __shfl_up(incl, off);
        if (lane >= off) incl += u;
    }
    if (lane == 63) wsum[w] = incl;
    __syncthreads();
    int base = 0;
    for (int i = 0; i < w; i++) base += wsum[i];
    int excl = base + incl - p;
    rs[2 * t] = excl;
    rs[2 * t + 1] = excl + v0;
    rowstart[nbase + 2 * t]     = region + excl;
    rowstart[nbase + 2 * t + 1] = region + excl + v0;
    dis[nbase + 2 * t]     = 1.0f / sqrtf((float)v0 + 1.0f);
    dis[nbase + 2 * t + 1] = 1.0f / sqrtf((float)v1 + 1.0f);
    if (g == 127 && t == 0) rowstart[NN] = EALL;
    __syncthreads();
    for (int i = 0; i < 32; i++) {
        int e = ebase + t + 256 * i;
        int d = dst_all[e] & 511;
        int pp = atomicAdd(&rs[d], 1);
        stage[pp] = src_all[e];
    }
    __syncthreads();
    for (int i = 0; i < 32; i++)
        csrc[region + t + 256 * i] = stage[t + 256 * i];
}

// ---------------- pooled CSR build ----------------
__global__ __launch_bounds__(256) void k_build_csr_pooled(const int* __restrict__ s1,
                                                          const int* __restrict__ d1,
                                                          const int* __restrict__ s2,
                                                          const int* __restrict__ d2,
                                                          const int* __restrict__ nmap,
                                                          int* __restrict__ rowstart,
                                                          int* __restrict__ cntp,
                                                          int* __restrict__ csre,
                                                          float* __restrict__ disp) {
    __shared__ int cnt[256];
    __shared__ int rs[256];
    __shared__ int wsum[4];
    __shared__ int stage[EPG];
    const int g = blockIdx.x;
    const int c = g >> 6, b = g & 63;
    const int* ss = c ? s2 : s1;
    const int* dd = c ? d2 : d1;
    const int* nm = nmap + c * 32768;
    const int ebase  = b * EPG;
    const int region = g * EPG;
    const int nbase  = g * 256;
    const int t = threadIdx.x;
    const int lane = t & 63, w = t >> 6;

    cnt[t] = 0;
    __syncthreads();
    for (int i = 0; i < 32; i++) {
        int e = ebase + t + 256 * i;
        int r = nm[ss[e]], cc = nm[dd[e]];
        if (r >= 0 && cc >= 0) atomicAdd(&cnt[cc & 255], 1);
    }
    __syncthreads();
    int v = cnt[t];
    int incl = v;
    for (int off = 1; off < 64; off <<= 1) {
        int u = __shfl_up(incl, off);
        if (lane >= off) incl += u;
    }
    if (lane == 63) wsum[w] = incl;
    __syncthreads();
    int base = 0;
    for (int i = 0; i < w; i++) base += wsum[i];
    int excl = base + incl - v;
    rs[t] = excl;
    rowstart[nbase + t] = region + excl;
    cntp[nbase + t] = v;
    disp[nbase + t] = 1.0f / sqrtf((float)v + 1.0f);
    __syncthreads();
    for (int i = 0; i < 32; i++) {
        int e = ebase + t + 256 * i;
        int r = nm[ss[e]], cc = nm[dd[e]];
        if (r >= 0 && cc >= 0) {
            int pp = atomicAdd(&rs[cc & 255], 1);
            stage[pp] = r;
        }
    }
    __syncthreads();
    for (int i = 0; i < 32; i++)
        csre[region + t + 256 * i] = stage[t + 256 * i];
}

// ---------------- fp32 GEMM (layers): C[M x 128] = A[M x KDIM] @ W, row-scaled ----------------
template <int KDIM>
__global__ __launch_bounds__(256) void k_gemm_tile(const float* __restrict__ A, int lda,
                                                   const float* __restrict__ W,
                                                   const float* __restrict__ rowscale,
                                                   float* __restrict__ C, int M) {
    __shared__ float As[32][132];
    __shared__ float Ws[32 * 128];
    const int tid  = threadIdx.x;
    const int c0 = (tid & 15) * 8;
    const int r0 = (tid >> 4) * 8;
    const int row0 = blockIdx.x * 128;
    const int arow = tid >> 1;
    const int aq   = tid & 1;
    const float* Ap = A + (size_t)(row0 + arow) * lda;
    const int pq0 = pq(c0 >> 2) * 4;
    const int pq1 = pq((c0 >> 2) + 1) * 4;

    float acc[8][8];
#pragma unroll
    for (int i = 0; i < 8; i++)
#pragma unroll
        for (int j = 0; j < 8; j++) acc[i][j] = 0.f;

    float4 areg[4], wreg[4];
#pragma unroll
    for (int qq = 0; qq < 4; qq++)
        areg[qq] = *(const float4*)(Ap + (aq + 2 * qq) * 4);
#pragma unroll
    for (int q = 0; q < 4; q++) {
        int f = tid + 256 * q;
        wreg[q] = *(const float4*)(W + (size_t)(f >> 5) * 128 + (f & 31) * 4);
    }

    constexpr int NT = KDIM / 32;
    for (int t = 0; t < NT; t++) {
#pragma unroll
        for (int qq = 0; qq < 4; qq++) {
            int kk = (aq + 2 * qq) * 4;
            As[kk + 0][arow] = areg[qq].x;
            As[kk + 1][arow] = areg[qq].y;
            As[kk + 2][arow] = areg[qq].z;
            As[kk + 3][arow] = areg[qq].w;
        }
#pragma unroll
        for (int q = 0; q < 4; q++) {
            int f = tid + 256 * q;
            *(float4*)&Ws[(f >> 5) * 128 + pq(f & 31) * 4] = wreg[q];
        }
        __syncthreads();
        if (t + 1 < NT) {
            int k0 = (t + 1) * 32;
#pragma unroll
            for (int qq = 0; qq < 4; qq++)
                areg[qq] = *(const float4*)(Ap + k0 + (aq + 2 * qq) * 4);
#pragma unroll
            for (int q = 0; q < 4; q++) {
                int f = tid + 256 * q;
                wreg[q] = *(const float4*)(W + (size_t)(k0 + (f >> 5)) * 128 + (f & 31) * 4);
            }
        }
#pragma unroll 2
        for (int kk = 0; kk < 32; kk++) {
            float4 a0 = *(const float4*)&As[kk][r0];
            float4 a1 = *(const float4*)&As[kk][r0 + 4];
            float4 b0 = *(const float4*)&Ws[kk * 128 + pq0];
            float4 b1 = *(const float4*)&Ws[kk * 128 + pq1];
            float a[8] = {a0.x, a0.y, a0.z, a0.w, a1.x, a1.y, a1.z, a1.w};
            float b[8] = {b0.x, b0.y, b0.z, b0.w, b1.x, b1.y, b1.z, b1.w};
#pragma unroll
            for (int i = 0; i < 8; i++)
#pragma unroll
                for (int j = 0; j < 8; j++)
                    acc[i][j] = fmaf(a[i], b[j], acc[i][j]);
        }
        if (t + 1 < NT) __syncthreads();
    }
#pragma unroll
    for (int i = 0; i < 8; i++) {
        int row = row0 + r0 + i;
        if (row < M) {
            float sc = rowscale[row];
            float4 o0 = {acc[i][0]*sc, acc[i][1]*sc, acc[i][2]*sc, acc[i][3]*sc};
            float4 o1 = {acc[i][4]*sc, acc[i][5]*sc, acc[i][6]*sc, acc[i][7]*sc};
            *(float4*)(C + (size_t)row * 128 + c0) = o0;
            *(float4*)(C + (size_t)row * 128 + c0 + 4) = o1;
        }
    }
}

// ---------------- Wf prep: transpose + bf16 hi/lo split ([n=128][k=384]) ----------------
__global__ void k_prep_wf(const float* __restrict__ Wf,
                          unsigned short* __restrict__ hi, unsigned short* __restrict__ lo) {
    int g = blockIdx.x * 256 + threadIdx.x;   // 0..49151
    int n = g / 384, k = g - n * 384;
    float v = Wf[k * 128 + n];
    unsigned short h = f2bf(v);
    hi[g] = h;
    lo[g] = f2bf(v - bf2f(h));
}

// ---------------- pooled gathered GEMM: MFMA bf16x3 (post-selection, continuous path) ----
__global__ __launch_bounds__(256) void k_gemm_gather_mfma(const float* __restrict__ XC,
                                                          const int* __restrict__ sel,
                                                          const float* __restrict__ SC,
                                                          const float* __restrict__ rowscale,
                                                          const unsigned short* __restrict__ WH,
                                                          const unsigned short* __restrict__ WL,
                                                          float* __restrict__ C) {
    __shared__ unsigned short Ah[128][40], Al[128][40], Wh[128][40], Wl[128][40];
    const int tid  = threadIdx.x;
    const int wid  = tid >> 6, lane = tid & 63;
    const int quad = lane >> 4, m15 = lane & 15;
    const int row0 = blockIdx.x * 128;
    const int arow = tid >> 1, aq = tid & 1;
    const int wn   = tid >> 1, wh2 = tid & 1;

    int n = row0 + arow;
    int comm = n >= NP;
    int nl = n - (comm ? NP : 0);
    int b = nl >> 8;
    int old = sel[n];
    const float* Ap = XC + (size_t)(b * NPB + comm * 512 + old) * 384;
    float scv = SC[comm * 32768 + b * 512 + old];
    float sg = 1.f / (1.f + expf(-scv));

    f32x4 acc[2][8];
#pragma unroll
    for (int i = 0; i < 2; i++)
#pragma unroll
        for (int j = 0; j < 8; j++) acc[i][j] = (f32x4){0.f, 0.f, 0.f, 0.f};

    float4 areg[4];
#pragma unroll
    for (int qq = 0; qq < 4; qq++)
        areg[qq] = *(const float4*)(Ap + (aq + 2 * qq) * 4);

    constexpr int NT = 12;
    for (int t = 0; t < NT; t++) {
        if (t) __syncthreads();
#pragma unroll
        for (int qq = 0; qq < 4; qq++) {
            int k = (aq + 2 * qq) * 4;
            float4 v = areg[qq];
            v.x *= sg; v.y *= sg; v.z *= sg; v.w *= sg;
            us4 h, l;
            h.x = f2bf(v.x); l.x = f2bf(v.x - bf2f(h.x));
            h.y = f2bf(v.y); l.y = f2bf(v.y - bf2f(h.y));
            h.z = f2bf(v.z); l.z = f2bf(v.z - bf2f(h.z));
            h.w = f2bf(v.w); l.w = f2bf(v.w - bf2f(h.w));
            *(us4*)&Ah[arow][k] = h;
            *(us4*)&Al[arow][k] = l;
        }
        int k0 = t * 32;
#pragma unroll
        for (int c = 0; c < 2; c++) {
            int kc = 8 * (wh2 + 2 * c);
            *(us8*)&Wh[wn][kc] = *(const us8*)&WH[(size_t)wn * 384 + k0 + kc];
            *(us8*)&Wl[wn][kc] = *(const us8*)&WL[(size_t)wn * 384 + k0 + kc];
        }
        __syncthreads();
        if (t + 1 < NT) {
            int kn = (t + 1) * 32;
#pragma unroll
            for (int qq = 0; qq < 4; qq++)
                areg[qq] = *(const float4*)(Ap + kn + (aq + 2 * qq) * 4);
        }
        bf16x8 ah[2], al2[2];
#pragma unroll
        for (int rt = 0; rt < 2; rt++) {
            int r = wid * 32 + rt * 16 + m15;
            ah[rt]  = *(const bf16x8*)&Ah[r][quad * 8];
            al2[rt] = *(const bf16x8*)&Al[r][quad * 8];
        }
#pragma unroll
        for (int ct = 0; ct < 8; ct++) {
            int nn = ct * 16 + m15;
            bf16x8 bh = *(const bf16x8*)&Wh[nn][quad * 8];
            bf16x8 bl = *(const bf16x8*)&Wl[nn][quad * 8];
#pragma unroll
            for (int rt = 0; rt < 2; rt++) {
                acc[rt][ct] = __builtin_amdgcn_mfma_f32_16x16x32_bf16(ah[rt], bh, acc[rt][ct], 0, 0, 0);
                acc[rt][ct] = __builtin_amdgcn_mfma_f32_16x16x32_bf16(al2[rt], bh, acc[rt][ct], 0, 0, 0);
                acc[rt][ct] = __builtin_amdgcn_mfma_f32_16x16x32_bf16(ah[rt], bl, acc[rt][ct], 0, 0, 0);
            }
        }
    }
    // C/D layout: col = lane&15, row = quad*4 + reg
#pragma unroll
    for (int rt = 0; rt < 2; rt++)
#pragma unroll
        for (int reg = 0; reg < 4; reg++) {
            int row = row0 + wid * 32 + rt * 16 + quad * 4 + reg;
            float sc = rowscale[row];
#pragma unroll
            for (int ct = 0; ct < 8; ct++)
                C[(size_t)row * 128 + ct * 16 + m15] = acc[rt][ct][reg] * sc;
        }
}

// ---------------- GCN aggregation (4-way edge-batched) + deterministic mean partials ----------
__global__ void k_aggregate4(const float* __restrict__ xwsc, const float* __restrict__ dis,
                             const int* __restrict__ rowstart, const int* __restrict__ csrc,
                             const float* __restrict__ bias, float* __restrict__ XC, int colbase,
                             float* __restrict__ mpart) {
    __shared__ float redf[8][128];
    int xcd  = blockIdx.x & 7;
    int slot = blockIdx.x >> 3;            // 0..1023
    int g    = ((slot >> 6) << 3) | xcd;   // 0..127
    int bslot = slot & 63;                 // within-group block slot (deterministic)
    int node = g * 512 + bslot * 8 + (threadIdx.x >> 5);
    int l    = threadIdx.x & 31;
    const float4* xw4 = (const float4*)xwsc;
    float4 acc = xw4[(size_t)node * 32 + l];
    int e0 = rowstart[node], e1 = rowstart[node + 1];
    int e = e0;
    // 4-way batched gather: 4 independent row loads in flight (latency hiding)
    for (; e + 4 <= e1; e += 4) {
        int s0 = csrc[e], s1 = csrc[e + 1], s2 = csrc[e + 2], s3 = csrc[e + 3];
        float4 u0 = xw4[(size_t)s0 * 32 + l];
        float4 u1 = xw4[(size_t)s1 * 32 + l];
        float4 u2 = xw4[(size_t)s2 * 32 + l];
        float4 u3 = xw4[(size_t)s3 * 32 + l];
        acc.x += (u0.x + u1.x) + (u2.x + u3.x);
        acc.y += (u0.y + u1.y) + (u2.y + u3.y);
        acc.z += (u0.z + u1.z) + (u2.z + u3.z);
        acc.w += (u0.w + u1.w) + (u2.w + u3.w);
    }
    for (; e < e1; e++) {
        int s = csrc[e];
        float4 u = xw4[(size_t)s * 32 + l];
        acc.x += u.x; acc.y += u.y; acc.z += u.z; acc.w += u.w;
    }
    float di = dis[node];
    float4 b4 = ((const float4*)bias)[l];
    acc.x = fmaxf(acc.x * di + b4.x, 0.f);
    acc.y = fmaxf(acc.y * di + b4.y, 0.f);
    acc.z = fmaxf(acc.z * di + b4.z, 0.f);
    acc.w = fmaxf(acc.w * di + b4.w, 0.f);
    *(float4*)(XC + (size_t)node * 384 + colbase + l * 4) = acc;
    *(float4*)&redf[threadIdx.x >> 5][l * 4] = acc;
    __syncthreads();
    if (threadIdx.x < 128) {
        int c = threadIdx.x;
        float s = 0.f;
#pragma unroll
        for (int r = 0; r < 8; r++) s += redf[r][c];
        mpart[((size_t)(g * 64 + bslot)) * 384 + colbase + c] = s;   // no atomics
    }
}

// pooled variant (4-way batched): fused H-mean partials (atomic OK — continuous path)
__global__ void k_aggregate_pooled(const float* __restrict__ xw, const float* __restrict__ disp,
                                   const int* __restrict__ rowstart, const int* __restrict__ cntp,
                                   const int* __restrict__ csre,
                                   const float* __restrict__ bias, float* __restrict__ H,
                                   float* __restrict__ meansum) {
    __shared__ float redf[8][128];
    int xcd  = blockIdx.x & 7;
    int slot = blockIdx.x >> 3;            // 0..511
    int g    = ((slot >> 5) << 3) | xcd;   // 0..127
    int node = g * 256 + (slot & 31) * 8 + (threadIdx.x >> 5);
    int l    = threadIdx.x & 31;
    const float4* x4 = (const float4*)xw;
    float4 acc = x4[(size_t)node * 32 + l];
    int e0 = rowstart[node], nE = cntp[node];
    int e = e0, eend = e0 + nE;
    for (; e + 4 <= eend; e += 4) {
        int s0 = csre[e], s1 = csre[e + 1], s2 = csre[e + 2], s3 = csre[e + 3];
        float4 u0 = x4[(size_t)s0 * 32 + l];
        float4 u1 = x4[(size_t)s1 * 32 + l];
        float4 u2 = x4[(size_t)s2 * 32 + l];
        float4 u3 = x4[(size_t)s3 * 32 + l];
        acc.x += (u0.x + u1.x) + (u2.x + u3.x);
        acc.y += (u0.y + u1.y) + (u2.y + u3.y);
        acc.z += (u0.z + u1.z) + (u2.z + u3.z);
        acc.w += (u0.w + u1.w) + (u2.w + u3.w);
    }
    for (; e < eend; e++) {
        int r = csre[e];
        float4 u = x4[(size_t)r * 32 + l];
        acc.x += u.x; acc.y += u.y; acc.z += u.z; acc.w += u.w;
    }
    float di = disp[node];
    float4 b4 = ((const float4*)bias)[l];
    acc.x = fmaxf(acc.x * di + b4.x, 0.f);
    acc.y = fmaxf(acc.y * di + b4.y, 0.f);
    acc.z = fmaxf(acc.z * di + b4.z, 0.f);
    acc.w = fmaxf(acc.w * di + b4.w, 0.f);
    *(float4*)(H + (size_t)node * 128 + l * 4) = acc;
    *(float4*)&redf[threadIdx.x >> 5][l * 4] = acc;
    __syncthreads();
    if (threadIdx.x < 128) {
        int c = threadIdx.x;
        float s = 0.f;
#pragma unroll
        for (int r = 0; r < 8; r++) s += redf[r][c];
        atomicAdd(&meansum[g * 128 + c], s);
    }
}

// ---------------- attention pool stage 1 ----------------
// c12 from deterministic mean partials (fixed-order 64-slot sum)
__global__ void k_c12(const float* __restrict__ mpart, const float* __restrict__ Wg,
                      float* __restrict__ c12) {
    __shared__ float ms[384];
    int seg = blockIdx.x; int c = threadIdx.x;   // 384 threads
    int g = ((seg & 63) << 1) | (seg >> 6);
    float s0 = 0.f;
    for (int s2 = 0; s2 < 64; s2++)
        s0 += mpart[((size_t)(g * 64 + s2)) * 384 + c];
    ms[c] = s0 * (1.0f / 512.0f);
    __syncthreads();
    float s = 0.f;
    for (int k = 0; k < 384; k++) s = fmaf(ms[k], Wg[(size_t)k * 384 + c], s);
    c12[seg * 384 + c] = tanhf(s);
}

// fused alpha+gp: each of 4 blocks per group writes a deterministic partial slot
__global__ __launch_bounds__(256) void k_attpool1(const float* __restrict__ XC,
                                                  const float* __restrict__ C12,
                                                  float* __restrict__ GPP) {
    __shared__ float gps[4][384];
    int blk = blockIdx.x;              // 0..511 (4 per group)
    int gc = blk >> 2, q = blk & 3;
    int seg = ((gc & 1) << 6) | (gc >> 1);
    int w = threadIdx.x >> 6, l = threadIdx.x & 63;
    const float* c12r = C12 + seg * 384;
    float4 cr0 = *(const float4*)(c12r + 4 * l);
    float4 cr1 = (l < 32) ? *(const float4*)(c12r + 256 + 4 * l) : float4{0.f,0.f,0.f,0.f};
    float4 a0 = {0.f,0.f,0.f,0.f}, a1 = {0.f,0.f,0.f,0.f};
    int base = gc * 512 + q * 128 + w * 32;
    for (int it = 0; it < 32; it++) {
        const float* xr = XC + (size_t)(base + it) * 384;
        float4 v0 = *(const float4*)(xr + 4 * l);
        float4 v1 = (l < 32) ? *(const float4*)(xr + 256 + 4 * l) : float4{0.f,0.f,0.f,0.f};
        float s = v0.x*cr0.x + v0.y*cr0.y + v0.z*cr0.z + v0.w*cr0.w
                + v1.x*cr1.x + v1.y*cr1.y + v1.z*cr1.z + v1.w*cr1.w;
        for (int off = 32; off; off >>= 1) s += __shfl_xor(s, off);
        float al = 1.f / (1.f + expf(-s));
        a0.x += v0.x*al; a0.y += v0.y*al; a0.z += v0.z*al; a0.w += v0.w*al;
        a1.x += v1.x*al; a1.y += v1.y*al; a1.z += v1.z*al; a1.w += v1.w*al;
    }
    *(float4*)&gps[w][4 * l] = a0;
    if (l < 32) *(float4*)&gps[w][256 + 4 * l] = a1;
    __syncthreads();
    for (int c = threadIdx.x; c < 384; c += 256) {
        float s = gps[0][c] + gps[1][c] + gps[2][c] + gps[3][c];
        GPP[(size_t)(seg * 4 + q) * 384 + c] = s;      // deterministic slot write
    }
}

// pv + fused pnorm; reduces the 4 GP partial slots in fixed order
__global__ void k_pv(const float* __restrict__ GPP, const float* __restrict__ Wal,
                     const float* __restrict__ bal, float* __restrict__ pv,
                     float* __restrict__ pnorm) {
    __shared__ float gpls[768];
    __shared__ float red[768];
    int row = blockIdx.x;               // 0..63
    int c   = threadIdx.x;              // 0..767
    {
        int seg = (c < 384) ? row : (64 + row);
        int k   = (c < 384) ? c : (c - 384);
        float v = GPP[(size_t)(seg * 4 + 0) * 384 + k] + GPP[(size_t)(seg * 4 + 1) * 384 + k]
                + GPP[(size_t)(seg * 4 + 2) * 384 + k] + GPP[(size_t)(seg * 4 + 3) * 384 + k];
        gpls[c] = v;
    }
    __syncthreads();
    float s = bal[c];
    for (int k = 0; k < 768; k++) s = fmaf(gpls[k], Wal[(size_t)k * 768 + c], s);
    pv[row * 768 + c] = s;
    red[c] = s * s;
    __syncthreads();
    int wv = c >> 6, ln = c & 63;
    if (wv < 2) {
        float s2 = 0.f;
#pragma unroll
        for (int i = 0; i < 6; i++) s2 += red[wv * 384 + ln + 64 * i];
        for (int off = 32; off; off >>= 1) s2 += __shfl_down(s2, off);
        if (ln == 0) pnorm[wv * 64 + row] = sqrtf(s2);
    }
}

// ---------------- scores (both communities) + per-batch top-K ----------------
__global__ void k_score(const float* __restrict__ XC, const float* __restrict__ pv,
                        const float* __restrict__ pnorm, float* __restrict__ sc) {
    int nl2 = blockIdx.x * 4 + (threadIdx.x >> 6);   // 0..65535
    int lane = threadIdx.x & 63;
    int comm = nl2 >> 15;
    int nl = nl2 & 32767;
    int b = nl >> 9; int i = nl & 511;
    const float* xr = XC + (size_t)(b * NPB + comm * 512 + i) * 384;
    const float* pr = pv + b * 768 + comm * 384;
    float4 x0 = *(const float4*)(xr + 4 * lane);
    float4 p0 = *(const float4*)(pr + 4 * lane);
    float s = x0.x*p0.x + x0.y*p0.y + x0.z*p0.z + x0.w*p0.w;
    if (lane < 32) {
        float4 x1 = *(const float4*)(xr + 256 + 4 * lane);
        float4 p1 = *(const float4*)(pr + 256 + 4 * lane);
        s += x1.x*p1.x + x1.y*p1.y + x1.z*p1.z + x1.w*p1.w;
    }
    for (int off = 32; off; off >>= 1) s += __shfl_down(s, off);
    if (lane == 0) sc[comm * 32768 + nl] = s / pnorm[comm * 64 + b];
}

__global__ void k_topk(const float* __restrict__ sc, int* __restrict__ sel, int* __restrict__ nmap) {
    __shared__ float sv[512];
    __shared__ int   si[512];
    int blk = blockIdx.x;               // 0..127 = comm*64 + b
    int t = threadIdx.x;                // 0..255
    sv[t] = sc[blk * 512 + t];             si[t] = t;
    sv[t + 256] = sc[blk * 512 + t + 256]; si[t + 256] = t + 256;
    __syncthreads();
    for (int k2 = 2; k2 <= 512; k2 <<= 1) {
        for (int j = k2 >> 1; j > 0; j >>= 1) {
            for (int i = t; i < 512; i += 256) {
                int l = i ^ j;
                if (l > i) {
                    bool desc = ((i & k2) == 0);
                    float a = sv[i], bb2 = sv[l];
                    bool sw = desc ? (a < bb2) : (a > bb2);
                    if (sw) {
                        sv[i] = bb2; sv[l] = a;
                        int tmp = si[i]; si[i] = si[l]; si[l] = tmp;
                    }
                }
            }
            __syncthreads();
        }
    }
    sel[blk * 256 + t] = si[t];
    nmap[blk * 512 + si[t]] = blk * 256 + t;
    nmap[blk * 512 + si[t + 256]] = -1;
}

// ---------------- final attention pool (fused alpha + weighted segment sum) ----------------
__global__ void k_cfin(const float* __restrict__ meansum, const float* __restrict__ Wg,
                       float* __restrict__ cf) {
    __shared__ float ms[128];
    int b = blockIdx.x; int c = threadIdx.x;
    ms[c] = meansum[b * 128 + c] * (1.0f / 256.0f);
    __syncthreads();
    float s = 0.f;
    for (int k = 0; k < 128; k++) s = fmaf(ms[k], Wg[k * 128 + c], s);
    cf[b * 128 + c] = tanhf(s);
}

__global__ __launch_bounds__(256) void k_attpool_fin(const float* __restrict__ H,
                                                     const float* __restrict__ cf,
                                                     float* __restrict__ g12) {
    __shared__ float gps[4][128];
    int seg = blockIdx.x;               // 0..127 = comm*64 + b
    int w = threadIdx.x >> 6, l = threadIdx.x & 63;
    const float2 cfl = *(const float2*)(cf + seg * 128 + 2 * l);
    float2 acc = {0.f, 0.f};
    int base = seg * 256 + w * 64;
    for (int it = 0; it < 64; it++) {
        const float2 h = *(const float2*)(H + (size_t)(base + it) * 128 + 2 * l);
        float s = h.x * cfl.x + h.y * cfl.y;
        for (int off = 32; off; off >>= 1) s += __shfl_xor(s, off);
        float al = 1.f / (1.f + expf(-s));
        acc.x += h.x * al; acc.y += h.y * al;
    }
    *(float2*)&gps[w][2 * l] = acc;
    __syncthreads();
    if (threadIdx.x < 128) {
        int c = threadIdx.x;
        float s = gps[0][c] + gps[1][c] + gps[2][c] + gps[3][c];
        int b = seg & 63, comm = seg >> 6;
        g12[b * 256 + comm * 128 + c] = s;
    }
}

// ---------------- MLP head ----------------
__global__ void k_mlp(const float* __restrict__ G,
                      const float* __restrict__ Wl1, const float* __restrict__ bl1,
                      const float* __restrict__ Wl2, const float* __restrict__ bl2,
                      const float* __restrict__ Wl3, const float* __restrict__ bl3,
                      float* __restrict__ out) {
    __shared__ float t1[128], t2[64];
    int b = blockIdx.x; int t = threadIdx.x;
    float s = bl1[t];
    for (int k = 0; k < 256; k++) s = fmaf(G[b * 256 + k], Wl1[k * 128 + t], s);
    t1[t] = fmaxf(s, 0.f);
    __syncthreads();
    if (t < 64) {
        float s2 = bl2[t];
        for (int k = 0; k < 128; k++) s2 = fmaf(t1[k], Wl2[k * 64 + t], s2);
        t2[t] = fmaxf(s2, 0.f);
    }
    __syncthreads();
    if (t < 2) {
        float s3 = bl3[t];
        for (int k = 0; k < 64; k++) s3 = fmaf(t2[k], Wl3[k * 2 + t], s3);
        out[b * 2 + t] = s3;
    }
}

// ---------------- launch ----------------
extern "C" void kernel_launch(void* const* d_in, const int* in_sizes, int n_in,
                              void* d_out, int out_size, void* d_ws, size_t ws_size,
                              hipStream_t stream) {
    const float* x       = (const float*)d_in[0];
    const int*   src_all = (const int*)d_in[1];
    const int*   dst_all = (const int*)d_in[2];
    const int*   src_c1  = (const int*)d_in[3];
    const int*   dst_c1  = (const int*)d_in[4];
    const int*   src_c2  = (const int*)d_in[5];
    const int*   dst_c2  = (const int*)d_in[6];
    const float* W1 = (const float*)d_in[7];   const float* b1 = (const float*)d_in[8];
    const float* W2 = (const float*)d_in[9];   const float* b2 = (const float*)d_in[10];
    const float* W3 = (const float*)d_in[11];  const float* b3 = (const float*)d_in[12];
    const float* Wg_att = (const float*)d_in[13];
    const float* Wal = (const float*)d_in[14]; const float* bal = (const float*)d_in[15];
    const float* Wf  = (const float*)d_in[16]; const float* bf  = (const float*)d_in[17];
    const float* Wg_fin = (const float*)d_in[18];
    const float* Wl1 = (const float*)d_in[19]; const float* bl1 = (const float*)d_in[20];
    const float* Wl2 = (const float*)d_in[21]; const float* bl2 = (const float*)d_in[22];
    const float* Wl3 = (const float*)d_in[23]; const float* bl3 = (const float*)d_in[24];
    float* out = (float*)d_out;

    // ---- workspace layout (floats) ----
    float* f = (float*)d_ws;
    size_t o = 0;
    float* XC   = f + o; o += (size_t)NN * 384;
    float* SCR  = f + o; o += (size_t)NN * 128;     // xw*dis; later XWP (NP2 x 128)
    float* H    = f + o; o += (size_t)NP2 * 128;    // pooled conv out; earlier aliased as MPART
    int* ROWSTART = (int*)(f + o); o += 65552;
    int* CSRC     = (int*)(f + o); o += EALL;
    int* CNTP     = (int*)(f + o); o += NP2;
    float* DIS    = f + o; o += NN;
    float* GPP    = f + o; o += 512 * 384;          // GP partial slots (deterministic)
    float* MEANF  = f + o; o += 128 * 128;          // atomic (continuous path)
    float* C12    = f + o; o += 128 * 384;
    float* PV     = f + o; o += 64 * 768;
    float* PNORM  = f + o; o += 128;
    float* SC     = f + o; o += 65536;
    int* SEL      = (int*)(f + o); o += NP2;
    int* NMAP     = (int*)(f + o); o += 65536;
    float* DISP   = f + o; o += NP2;
    float* CFIN   = f + o; o += 128 * 128;
    float* G12    = f + o; o += 64 * 256;
    unsigned short* WBH = (unsigned short*)(f + o); o += 24576;   // 49152 bf16
    unsigned short* WBL = (unsigned short*)(f + o); o += 24576;
    size_t needed_bytes = o * sizeof(float);
    if (ws_size < needed_bytes) return;

    float* MPART = H;                   // 128*64*384 = 3.1M floats <= H (4.2M) — H written later
    float* XWP   = SCR;                 // pooled GEMM output (NP2 x 128), reuses SCR

    // zero the remaining atomic accumulator (MEANF only)
    hipMemsetAsync(MEANF, 0, 128 * 128 * sizeof(float), stream);

    // ---- Wf prep (transpose + bf16 hi/lo) ----
    k_prep_wf<<<192, 256, 0, stream>>>(Wf, WBH, WBL);

    // ---- full-graph CSR + degrees ----
    k_build_csr<<<128, 256, 0, stream>>>(src_all, dst_all, ROWSTART, CSRC, DIS);

    // ---- 3 GCN layers (fp32 GEMM keeps the selection path bit-stable) ----
    k_gemm_tile<128><<<NN / 128, 256, 0, stream>>>(x, 128, W1, DIS, SCR, NN);
    k_aggregate4<<<NN / 8, 256, 0, stream>>>(SCR, DIS, ROWSTART, CSRC, b1, XC, 0, MPART);
    k_gemm_tile<128><<<NN / 128, 256, 0, stream>>>(XC + 0, 384, W2, DIS, SCR, NN);
    k_aggregate4<<<NN / 8, 256, 0, stream>>>(SCR, DIS, ROWSTART, CSRC, b2, XC, 128, MPART);
    k_gemm_tile<128><<<NN / 128, 256, 0, stream>>>(XC + 128, 384, W3, DIS, SCR, NN);
    k_aggregate4<<<NN / 8, 256, 0, stream>>>(SCR, DIS, ROWSTART, CSRC, b3, XC, 256, MPART);

    // ---- attention pool over communities (deterministic reductions) ----
    k_c12<<<128, 384, 0, stream>>>(MPART, Wg_att, C12);
    k_attpool1<<<512, 256, 0, stream>>>(XC, C12, GPP);
    k_pv<<<64, 768, 0, stream>>>(GPP, Wal, bal, PV, PNORM);

    // ---- scores + top-K ----
    k_score<<<65536 / 4, 256, 0, stream>>>(XC, PV, PNORM, SC);
    k_topk<<<128, 256, 0, stream>>>(SC, SEL, NMAP);

    // ---- pooled graph build ----
    k_build_csr_pooled<<<128, 256, 0, stream>>>(src_c1, dst_c1, src_c2, dst_c2,
                                                NMAP, ROWSTART, CNTP, CSRC, DISP);

    // ---- pooled GCN (MFMA bf16x3 gathered GEMM — post-selection, continuous path) ----
    k_gemm_gather_mfma<<<NP2 / 128, 256, 0, stream>>>(XC, SEL, SC, DISP, WBH, WBL, XWP);
    k_aggregate_pooled<<<NP2 / 8, 256, 0, stream>>>(XWP, DISP, ROWSTART, CNTP, CSRC,
                                                    bf, H, MEANF);

    // ---- final attention pool (fused) ----
    k_cfin<<<128, 128, 0, stream>>>(MEANF, Wg_fin, CFIN);
    k_attpool_fin<<<128, 256, 0, stream>>>(H, CFIN, G12);

    // ---- MLP head ----
    k_mlp<<<64, 128, 0, stream>>>(G12, Wl1, bl1, Wl2, bl2, Wl3, bl3, out);
}

// Round 11
// 512.783 us; speedup vs baseline: 1.3224x; 1.1218x over previous
//
#include <hip/hip_runtime.h>
#include <math.h>

// ---------------- constants ----------------
constexpr int BB   = 64;
constexpr int NPB  = 1024;            // nodes per batch graph (N1+N2)
constexpr int NN   = BB * NPB;        // 65536 total nodes
constexpr int EALL = 1048576;         // total edges (both communities)
constexpr int EC   = 524288;          // edges per community
constexpr int EPG  = 8192;            // edges per (batch,community) group == N1*DEG
constexpr int KTOP = 256;             // K1 == K2
constexpr int NP   = BB * KTOP;       // 16384 pooled nodes per community
constexpr int NP2  = 2 * NP;          // 32768 pooled nodes total

typedef __attribute__((ext_vector_type(8))) short bf16x8;
typedef __attribute__((ext_vector_type(4))) unsigned short us4;
typedef __attribute__((ext_vector_type(8))) unsigned short us8;
typedef __attribute__((ext_vector_type(4))) float f32x4;

__device__ __forceinline__ unsigned short f2bf(float f) {      // truncation split
    return (unsigned short)(__float_as_uint(f) >> 16);
}
__device__ __forceinline__ float bf2f(unsigned short h) {
    return __uint_as_float(((unsigned)h) << 16);
}

// ---------------- full-graph CSR build: per-group LDS counting sort ----------------
__global__ __launch_bounds__(256) void k_build_csr(const int* __restrict__ src_all,
                                                   const int* __restrict__ dst_all,
                                                   int* __restrict__ rowstart,
                                                   int* __restrict__ csrc,
                                                   float* __restrict__ dis) {
    __shared__ int cnt[512];
    __shared__ int rs[512];
    __shared__ int wsum[4];
    __shared__ int stage[EPG];
    const int g = blockIdx.x;
    const int b = g >> 1, c = g & 1;
    const int ebase  = c * EC + b * EPG;
    const int region = g * EPG;
    const int nbase  = g * 512;
    const int t = threadIdx.x;
    const int lane = t & 63, w = t >> 6;

    cnt[t] = 0; cnt[t + 256] = 0;
    __syncthreads();
    for (int i = 0; i < 32; i++) {
        int d = dst_all[ebase + t + 256 * i] & 511;
        atomicAdd(&cnt[d], 1);
    }
    __syncthreads();
    int v0 = cnt[2 * t], v1 = cnt[2 * t + 1];
    int p = v0 + v1;
    int incl = p;
    for (int off = 1; off < 64; off <<= 1) {
        int u = __shfl_up(incl, off);
        if (lane >= off) incl += u;
    }
    if (lane == 63) wsum[w] = incl;
    __syncthreads();
    int base = 0;
    for (int i = 0; i < w; i++) base += wsum[i];
    int excl = base + incl - p;
    rs[2 * t] = excl;
    rs[2 * t + 1] = excl + v0;
    rowstart[nbase + 2 * t]     = region + excl;
    rowstart[nbase + 2 * t + 1] = region + excl + v0;
    dis[nbase + 2 * t]     = 1.0f / sqrtf((float)v0 + 1.0f);
    dis[nbase + 2 * t + 1] = 1.0f / sqrtf((float)v1 + 1.0f);
    if (g == 127 && t == 0) rowstart[NN] = EALL;
    __syncthreads();
    for (int i = 0; i < 32; i++) {
        int e = ebase + t + 256 * i;
        int d = dst_all[e] & 511;
        int pp = atomicAdd(&rs[d], 1);
        stage[pp] = src_all[e];
    }
    __syncthreads();
    for (int i = 0; i < 32; i++)
        csrc[region + t + 256 * i] = stage[t + 256 * i];
}

// ---------------- pooled CSR build ----------------
__global__ __launch_bounds__(256) void k_build_csr_pooled(const int* __restrict__ s1,
                                                          const int* __restrict__ d1,
                                                          const int* __restrict__ s2,
                                                          const int* __restrict__ d2,
                                                          const int* __restrict__ nmap,
                                                          int* __restrict__ rowstart,
                                                          int* __restrict__ cntp,
                                                          int* __restrict__ csre,
                                                          float* __restrict__ disp) {
    __shared__ int cnt[256];
    __shared__ int rs[256];
    __shared__ int wsum[4];
    __shared__ int stage[EPG];
    const int g = blockIdx.x;
    const int c = g >> 6, b = g & 63;
    const int* ss = c ? s2 : s1;
    const int* dd = c ? d2 : d1;
    const int* nm = nmap + c * 32768;
    const int ebase  = b * EPG;
    const int region = g * EPG;
    const int nbase  = g * 256;
    const int t = threadIdx.x;
    const int lane = t & 63, w = t >> 6;

    cnt[t] = 0;
    __syncthreads();
    for (int i = 0; i < 32; i++) {
        int e = ebase + t + 256 * i;
        int r = nm[ss[e]], cc = nm[dd[e]];
        if (r >= 0 && cc >= 0) atomicAdd(&cnt[cc & 255], 1);
    }
    __syncthreads();
    int v = cnt[t];
    int incl = v;
    for (int off = 1; off < 64; off <<= 1) {
        int u = __shfl_up(incl, off);
        if (lane >= off) incl += u;
    }
    if (lane == 63) wsum[w] = incl;
    __syncthreads();
    int base = 0;
    for (int i = 0; i < w; i++) base += wsum[i];
    int excl = base + incl - v;
    rs[t] = excl;
    rowstart[nbase + t] = region + excl;
    cntp[nbase + t] = v;
    disp[nbase + t] = 1.0f / sqrtf((float)v + 1.0f);
    __syncthreads();
    for (int i = 0; i < 32; i++) {
        int e = ebase + t + 256 * i;
        int r = nm[ss[e]], cc = nm[dd[e]];
        if (r >= 0 && cc >= 0) {
            int pp = atomicAdd(&rs[cc & 255], 1);
            stage[pp] = r;
        }
    }
    __syncthreads();
    for (int i = 0; i < 32; i++)
        csre[region + t + 256 * i] = stage[t + 256 * i];
}

// ---------------- W prep: transpose + bf16 hi/lo split ----------------
// layout: W1 hi at [0,16384) as [n=128][k=128]; W2 +16384; W3 +32768; Wf at +49152 as [n=128][k=384]
__global__ void k_prep_w(const float* __restrict__ W1, const float* __restrict__ W2,
                         const float* __restrict__ W3, const float* __restrict__ Wf,
                         unsigned short* __restrict__ hi, unsigned short* __restrict__ lo) {
    int g = blockIdx.x * 256 + threadIdx.x;   // 0..98303
    float v; int dst;
    if (g < 49152) {
        int mat = g >> 14, rem = g & 16383;
        int n = rem >> 7, k = rem & 127;
        const float* W = (mat == 0) ? W1 : (mat == 1) ? W2 : W3;
        v = W[k * 128 + n];
        dst = mat * 16384 + n * 128 + k;
    } else {
        int rem = g - 49152;
        int n = rem / 384, k = rem - n * 384;
        v = Wf[k * 128 + n];
        dst = 49152 + n * 384 + k;
    }
    unsigned short h = f2bf(v);
    hi[dst] = h;
    lo[dst] = f2bf(v - bf2f(h));
}

// ---------------- MFMA GEMM (layers): C[M x 128] = A[M x 128] @ W, row-scaled --------------
// bf16x3 error-compensated (deterministic). 128x128 tile, 256 thr = 4 waves,
// each wave 32 rows x 128 cols. A fp32 global -> hi/lo bf16 LDS; W pre-split bf16.
template <int KDIM>
__global__ __launch_bounds__(256) void k_gemm_mfma(const float* __restrict__ A, int lda,
                                                   const unsigned short* __restrict__ WH,
                                                   const unsigned short* __restrict__ WL,
                                                   const float* __restrict__ rowscale,
                                                   float* __restrict__ C) {
    __shared__ unsigned short Ah[128][40], Al[128][40], Wh[128][40], Wl[128][40];
    const int tid  = threadIdx.x;
    const int wid  = tid >> 6, lane = tid & 63;
    const int quad = lane >> 4, m15 = lane & 15;
    const int row0 = blockIdx.x * 128;
    const int arow = tid >> 1, aq = tid & 1;
    const int wn   = tid >> 1, wh2 = tid & 1;
    const float* Ap = A + (size_t)(row0 + arow) * lda;

    f32x4 acc[2][8];
#pragma unroll
    for (int i = 0; i < 2; i++)
#pragma unroll
        for (int j = 0; j < 8; j++) acc[i][j] = (f32x4){0.f, 0.f, 0.f, 0.f};

    float4 areg[4];
#pragma unroll
    for (int qq = 0; qq < 4; qq++)
        areg[qq] = *(const float4*)(Ap + (aq + 2 * qq) * 4);

    constexpr int NT = KDIM / 32;
    for (int t = 0; t < NT; t++) {
        if (t) __syncthreads();
#pragma unroll
        for (int qq = 0; qq < 4; qq++) {
            int k = (aq + 2 * qq) * 4;
            float4 v = areg[qq];
            us4 h, l;
            h.x = f2bf(v.x); l.x = f2bf(v.x - bf2f(h.x));
            h.y = f2bf(v.y); l.y = f2bf(v.y - bf2f(h.y));
            h.z = f2bf(v.z); l.z = f2bf(v.z - bf2f(h.z));
            h.w = f2bf(v.w); l.w = f2bf(v.w - bf2f(h.w));
            *(us4*)&Ah[arow][k] = h;
            *(us4*)&Al[arow][k] = l;
        }
        int k0 = t * 32;
#pragma unroll
        for (int c = 0; c < 2; c++) {
            int kc = 8 * (wh2 + 2 * c);
            *(us8*)&Wh[wn][kc] = *(const us8*)&WH[(size_t)wn * KDIM + k0 + kc];
            *(us8*)&Wl[wn][kc] = *(const us8*)&WL[(size_t)wn * KDIM + k0 + kc];
        }
        __syncthreads();
        if (t + 1 < NT) {
            int kn = (t + 1) * 32;
#pragma unroll
            for (int qq = 0; qq < 4; qq++)
                areg[qq] = *(const float4*)(Ap + kn + (aq + 2 * qq) * 4);
        }
        bf16x8 ah[2], al2[2];
#pragma unroll
        for (int rt = 0; rt < 2; rt++) {
            int r = wid * 32 + rt * 16 + m15;
            ah[rt]  = *(const bf16x8*)&Ah[r][quad * 8];
            al2[rt] = *(const bf16x8*)&Al[r][quad * 8];
        }
#pragma unroll
        for (int ct = 0; ct < 8; ct++) {
            int n = ct * 16 + m15;
            bf16x8 bh = *(const bf16x8*)&Wh[n][quad * 8];
            bf16x8 bl = *(const bf16x8*)&Wl[n][quad * 8];
#pragma unroll
            for (int rt = 0; rt < 2; rt++) {
                acc[rt][ct] = __builtin_amdgcn_mfma_f32_16x16x32_bf16(ah[rt], bh, acc[rt][ct], 0, 0, 0);
                acc[rt][ct] = __builtin_amdgcn_mfma_f32_16x16x32_bf16(al2[rt], bh, acc[rt][ct], 0, 0, 0);
                acc[rt][ct] = __builtin_amdgcn_mfma_f32_16x16x32_bf16(ah[rt], bl, acc[rt][ct], 0, 0, 0);
            }
        }
    }
    // C/D layout: col = lane&15, row = quad*4 + reg  [verified m89]
#pragma unroll
    for (int rt = 0; rt < 2; rt++)
#pragma unroll
        for (int reg = 0; reg < 4; reg++) {
            int row = row0 + wid * 32 + rt * 16 + quad * 4 + reg;
            float sc = rowscale[row];
#pragma unroll
            for (int ct = 0; ct < 8; ct++)
                C[(size_t)row * 128 + ct * 16 + m15] = acc[rt][ct][reg] * sc;
        }
}

// ---------------- pooled gathered GEMM: MFMA bf16x3 (post-selection) ----------------
__global__ __launch_bounds__(256) void k_gemm_gather_mfma(const float* __restrict__ XC,
                                                          const int* __restrict__ sel,
                                                          const float* __restrict__ SC,
                                                          const float* __restrict__ rowscale,
                                                          const unsigned short* __restrict__ WH,
                                                          const unsigned short* __restrict__ WL,
                                                          float* __restrict__ C) {
    __shared__ unsigned short Ah[128][40], Al[128][40], Wh[128][40], Wl[128][40];
    const int tid  = threadIdx.x;
    const int wid  = tid >> 6, lane = tid & 63;
    const int quad = lane >> 4, m15 = lane & 15;
    const int row0 = blockIdx.x * 128;
    const int arow = tid >> 1, aq = tid & 1;
    const int wn   = tid >> 1, wh2 = tid & 1;

    int n = row0 + arow;
    int comm = n >= NP;
    int nl = n - (comm ? NP : 0);
    int b = nl >> 8;
    int old = sel[n];
    const float* Ap = XC + (size_t)(b * NPB + comm * 512 + old) * 384;
    float scv = SC[comm * 32768 + b * 512 + old];
    float sg = 1.f / (1.f + expf(-scv));

    f32x4 acc[2][8];
#pragma unroll
    for (int i = 0; i < 2; i++)
#pragma unroll
        for (int j = 0; j < 8; j++) acc[i][j] = (f32x4){0.f, 0.f, 0.f, 0.f};

    float4 areg[4];
#pragma unroll
    for (int qq = 0; qq < 4; qq++)
        areg[qq] = *(const float4*)(Ap + (aq + 2 * qq) * 4);

    constexpr int NT = 12;
    for (int t = 0; t < NT; t++) {
        if (t) __syncthreads();
#pragma unroll
        for (int qq = 0; qq < 4; qq++) {
            int k = (aq + 2 * qq) * 4;
            float4 v = areg[qq];
            v.x *= sg; v.y *= sg; v.z *= sg; v.w *= sg;
            us4 h, l;
            h.x = f2bf(v.x); l.x = f2bf(v.x - bf2f(h.x));
            h.y = f2bf(v.y); l.y = f2bf(v.y - bf2f(h.y));
            h.z = f2bf(v.z); l.z = f2bf(v.z - bf2f(h.z));
            h.w = f2bf(v.w); l.w = f2bf(v.w - bf2f(h.w));
            *(us4*)&Ah[arow][k] = h;
            *(us4*)&Al[arow][k] = l;
        }
        int k0 = t * 32;
#pragma unroll
        for (int c = 0; c < 2; c++) {
            int kc = 8 * (wh2 + 2 * c);
            *(us8*)&Wh[wn][kc] = *(const us8*)&WH[(size_t)wn * 384 + k0 + kc];
            *(us8*)&Wl[wn][kc] = *(const us8*)&WL[(size_t)wn * 384 + k0 + kc];
        }
        __syncthreads();
        if (t + 1 < NT) {
            int kn = (t + 1) * 32;
#pragma unroll
            for (int qq = 0; qq < 4; qq++)
                areg[qq] = *(const float4*)(Ap + kn + (aq + 2 * qq) * 4);
        }
        bf16x8 ah[2], al2[2];
#pragma unroll
        for (int rt = 0; rt < 2; rt++) {
            int r = wid * 32 + rt * 16 + m15;
            ah[rt]  = *(const bf16x8*)&Ah[r][quad * 8];
            al2[rt] = *(const bf16x8*)&Al[r][quad * 8];
        }
#pragma unroll
        for (int ct = 0; ct < 8; ct++) {
            int nn = ct * 16 + m15;
            bf16x8 bh = *(const bf16x8*)&Wh[nn][quad * 8];
            bf16x8 bl = *(const bf16x8*)&Wl[nn][quad * 8];
#pragma unroll
            for (int rt = 0; rt < 2; rt++) {
                acc[rt][ct] = __builtin_amdgcn_mfma_f32_16x16x32_bf16(ah[rt], bh, acc[rt][ct], 0, 0, 0);
                acc[rt][ct] = __builtin_amdgcn_mfma_f32_16x16x32_bf16(al2[rt], bh, acc[rt][ct], 0, 0, 0);
                acc[rt][ct] = __builtin_amdgcn_mfma_f32_16x16x32_bf16(ah[rt], bl, acc[rt][ct], 0, 0, 0);
            }
        }
    }
#pragma unroll
    for (int rt = 0; rt < 2; rt++)
#pragma unroll
        for (int reg = 0; reg < 4; reg++) {
            int row = row0 + wid * 32 + rt * 16 + quad * 4 + reg;
            float sc = rowscale[row];
#pragma unroll
            for (int ct = 0; ct < 8; ct++)
                C[(size_t)row * 128 + ct * 16 + m15] = acc[rt][ct][reg] * sc;
        }
}

// ---------------- GCN aggregation (4-way edge-batched) + deterministic mean partials ----------
__global__ void k_aggregate4(const float* __restrict__ xwsc, const float* __restrict__ dis,
                             const int* __restrict__ rowstart, const int* __restrict__ csrc,
                             const float* __restrict__ bias, float* __restrict__ XC, int colbase,
                             float* __restrict__ mpart) {
    __shared__ float redf[8][128];
    int xcd  = blockIdx.x & 7;
    int slot = blockIdx.x >> 3;            // 0..1023
    int g    = ((slot >> 6) << 3) | xcd;   // 0..127
    int bslot = slot & 63;                 // within-group block slot (deterministic)
    int node = g * 512 + bslot * 8 + (threadIdx.x >> 5);
    int l    = threadIdx.x & 31;
    const float4* xw4 = (const float4*)xwsc;
    float4 acc = xw4[(size_t)node * 32 + l];
    int e0 = rowstart[node], e1 = rowstart[node + 1];
    int e = e0;
    for (; e + 4 <= e1; e += 4) {
        int s0 = csrc[e], s1 = csrc[e + 1], s2 = csrc[e + 2], s3 = csrc[e + 3];
        float4 u0 = xw4[(size_t)s0 * 32 + l];
        float4 u1 = xw4[(size_t)s1 * 32 + l];
        float4 u2 = xw4[(size_t)s2 * 32 + l];
        float4 u3 = xw4[(size_t)s3 * 32 + l];
        acc.x += (u0.x + u1.x) + (u2.x + u3.x);
        acc.y += (u0.y + u1.y) + (u2.y + u3.y);
        acc.z += (u0.z + u1.z) + (u2.z + u3.z);
        acc.w += (u0.w + u1.w) + (u2.w + u3.w);
    }
    for (; e < e1; e++) {
        int s = csrc[e];
        float4 u = xw4[(size_t)s * 32 + l];
        acc.x += u.x; acc.y += u.y; acc.z += u.z; acc.w += u.w;
    }
    float di = dis[node];
    float4 b4 = ((const float4*)bias)[l];
    acc.x = fmaxf(acc.x * di + b4.x, 0.f);
    acc.y = fmaxf(acc.y * di + b4.y, 0.f);
    acc.z = fmaxf(acc.z * di + b4.z, 0.f);
    acc.w = fmaxf(acc.w * di + b4.w, 0.f);
    *(float4*)(XC + (size_t)node * 384 + colbase + l * 4) = acc;
    *(float4*)&redf[threadIdx.x >> 5][l * 4] = acc;
    __syncthreads();
    if (threadIdx.x < 128) {
        int c = threadIdx.x;
        float s = 0.f;
#pragma unroll
        for (int r = 0; r < 8; r++) s += redf[r][c];
        mpart[((size_t)(g * 64 + bslot)) * 384 + colbase + c] = s;   // no atomics
    }
}

// pooled variant (4-way batched): fused H-mean partials (atomic OK — continuous path)
__global__ void k_aggregate_pooled(const float* __restrict__ xw, const float* __restrict__ disp,
                                   const int* __restrict__ rowstart, const int* __restrict__ cntp,
                                   const int* __restrict__ csre,
                                   const float* __restrict__ bias, float* __restrict__ H,
                                   float* __restrict__ meansum) {
    __shared__ float redf[8][128];
    int xcd  = blockIdx.x & 7;
    int slot = blockIdx.x >> 3;            // 0..511
    int g    = ((slot >> 5) << 3) | xcd;   // 0..127
    int node = g * 256 + (slot & 31) * 8 + (threadIdx.x >> 5);
    int l    = threadIdx.x & 31;
    const float4* x4 = (const float4*)xw;
    float4 acc = x4[(size_t)node * 32 + l];
    int e0 = rowstart[node], nE = cntp[node];
    int e = e0, eend = e0 + nE;
    for (; e + 4 <= eend; e += 4) {
        int s0 = csre[e], s1 = csre[e + 1], s2 = csre[e + 2], s3 = csre[e + 3];
        float4 u0 = x4[(size_t)s0 * 32 + l];
        float4 u1 = x4[(size_t)s1 * 32 + l];
        float4 u2 = x4[(size_t)s2 * 32 + l];
        float4 u3 = x4[(size_t)s3 * 32 + l];
        acc.x += (u0.x + u1.x) + (u2.x + u3.x);
        acc.y += (u0.y + u1.y) + (u2.y + u3.y);
        acc.z += (u0.z + u1.z) + (u2.z + u3.z);
        acc.w += (u0.w + u1.w) + (u2.w + u3.w);
    }
    for (; e < eend; e++) {
        int r = csre[e];
        float4 u = x4[(size_t)r * 32 + l];
        acc.x += u.x; acc.y += u.y; acc.z += u.z; acc.w += u.w;
    }
    float di = disp[node];
    float4 b4 = ((const float4*)bias)[l];
    acc.x = fmaxf(acc.x * di + b4.x, 0.f);
    acc.y = fmaxf(acc.y * di + b4.y, 0.f);
    acc.z = fmaxf(acc.z * di + b4.z, 0.f);
    acc.w = fmaxf(acc.w * di + b4.w, 0.f);
    *(float4*)(H + (size_t)node * 128 + l * 4) = acc;
    *(float4*)&redf[threadIdx.x >> 5][l * 4] = acc;
    __syncthreads();
    if (threadIdx.x < 128) {
        int c = threadIdx.x;
        float s = 0.f;
#pragma unroll
        for (int r = 0; r < 8; r++) s += redf[r][c];
        atomicAdd(&meansum[g * 128 + c], s);
    }
}

// ---------------- attention pool stage 1 ----------------
__global__ void k_c12(const float* __restrict__ mpart, const float* __restrict__ Wg,
                      float* __restrict__ c12) {
    __shared__ float ms[384];
    int seg = blockIdx.x; int c = threadIdx.x;   // 384 threads
    int g = ((seg & 63) << 1) | (seg >> 6);
    float s0 = 0.f;
    for (int s2 = 0; s2 < 64; s2++)
        s0 += mpart[((size_t)(g * 64 + s2)) * 384 + c];
    ms[c] = s0 * (1.0f / 512.0f);
    __syncthreads();
    float s = 0.f;
    for (int k = 0; k < 384; k++) s = fmaf(ms[k], Wg[(size_t)k * 384 + c], s);
    c12[seg * 384 + c] = tanhf(s);
}

__global__ __launch_bounds__(256) void k_attpool1(const float* __restrict__ XC,
                                                  const float* __restrict__ C12,
                                                  float* __restrict__ GPP) {
    __shared__ float gps[4][384];
    int blk = blockIdx.x;              // 0..511 (4 per group)
    int gc = blk >> 2, q = blk & 3;
    int seg = ((gc & 1) << 6) | (gc >> 1);
    int w = threadIdx.x >> 6, l = threadIdx.x & 63;
    const float* c12r = C12 + seg * 384;
    float4 cr0 = *(const float4*)(c12r + 4 * l);
    float4 cr1 = (l < 32) ? *(const float4*)(c12r + 256 + 4 * l) : float4{0.f,0.f,0.f,0.f};
    float4 a0 = {0.f,0.f,0.f,0.f}, a1 = {0.f,0.f,0.f,0.f};
    int base = gc * 512 + q * 128 + w * 32;
    for (int it = 0; it < 32; it++) {
        const float* xr = XC + (size_t)(base + it) * 384;
        float4 v0 = *(const float4*)(xr + 4 * l);
        float4 v1 = (l < 32) ? *(const float4*)(xr + 256 + 4 * l) : float4{0.f,0.f,0.f,0.f};
        float s = v0.x*cr0.x + v0.y*cr0.y + v0.z*cr0.z + v0.w*cr0.w
                + v1.x*cr1.x + v1.y*cr1.y + v1.z*cr1.z + v1.w*cr1.w;
        for (int off = 32; off; off >>= 1) s += __shfl_xor(s, off);
        float al = 1.f / (1.f + expf(-s));
        a0.x += v0.x*al; a0.y += v0.y*al; a0.z += v0.z*al; a0.w += v0.w*al;
        a1.x += v1.x*al; a1.y += v1.y*al; a1.z += v1.z*al; a1.w += v1.w*al;
    }
    *(float4*)&gps[w][4 * l] = a0;
    if (l < 32) *(float4*)&gps[w][256 + 4 * l] = a1;
    __syncthreads();
    for (int c = threadIdx.x; c < 384; c += 256) {
        float s = gps[0][c] + gps[1][c] + gps[2][c] + gps[3][c];
        GPP[(size_t)(seg * 4 + q) * 384 + c] = s;      // deterministic slot write
    }
}

// pv + fused pnorm; reduces the 4 GP partial slots in fixed order
__global__ void k_pv(const float* __restrict__ GPP, const float* __restrict__ Wal,
                     const float* __restrict__ bal, float* __restrict__ pv,
                     float* __restrict__ pnorm) {
    __shared__ float gpls[768];
    __shared__ float red[768];
    int row = blockIdx.x;               // 0..63
    int c   = threadIdx.x;              // 0..767
    {
        int seg = (c < 384) ? row : (64 + row);
        int k   = (c < 384) ? c : (c - 384);
        float v = GPP[(size_t)(seg * 4 + 0) * 384 + k] + GPP[(size_t)(seg * 4 + 1) * 384 + k]
                + GPP[(size_t)(seg * 4 + 2) * 384 + k] + GPP[(size_t)(seg * 4 + 3) * 384 + k];
        gpls[c] = v;
    }
    __syncthreads();
    float s = bal[c];
    for (int k = 0; k < 768; k++) s = fmaf(gpls[k], Wal[(size_t)k * 768 + c], s);
    pv[row * 768 + c] = s;
    red[c] = s * s;
    __syncthreads();
    int wv = c >> 6, ln = c & 63;
    if (wv < 2) {
        float s2 = 0.f;
#pragma unroll
        for (int i = 0; i < 6; i++) s2 += red[wv * 384 + ln + 64 * i];
        for (int off = 32; off; off >>= 1) s2 += __shfl_down(s2, off);
        if (ln == 0) pnorm[wv * 64 + row] = sqrtf(s2);
    }
}

// ---------------- scores (both communities) + per-batch top-K ----------------
__global__ void k_score(const float* __restrict__ XC, const float* __restrict__ pv,
                        const float* __restrict__ pnorm, float* __restrict__ sc) {
    int nl2 = blockIdx.x * 4 + (threadIdx.x >> 6);   // 0..65535
    int lane = threadIdx.x & 63;
    int comm = nl2 >> 15;
    int nl = nl2 & 32767;
    int b = nl >> 9; int i = nl & 511;
    const float* xr = XC + (size_t)(b * NPB + comm * 512 + i) * 384;
    const float* pr = pv + b * 768 + comm * 384;
    float4 x0 = *(const float4*)(xr + 4 * lane);
    float4 p0 = *(const float4*)(pr + 4 * lane);
    float s = x0.x*p0.x + x0.y*p0.y + x0.z*p0.z + x0.w*p0.w;
    if (lane < 32) {
        float4 x1 = *(const float4*)(xr + 256 + 4 * lane);
        float4 p1 = *(const float4*)(pr + 256 + 4 * lane);
        s += x1.x*p1.x + x1.y*p1.y + x1.z*p1.z + x1.w*p1.w;
    }
    for (int off = 32; off; off >>= 1) s += __shfl_down(s, off);
    if (lane == 0) sc[comm * 32768 + nl] = s / pnorm[comm * 64 + b];
}

__global__ void k_topk(const float* __restrict__ sc, int* __restrict__ sel, int* __restrict__ nmap) {
    __shared__ float sv[512];
    __shared__ int   si[512];
    int blk = blockIdx.x;               // 0..127 = comm*64 + b
    int t = threadIdx.x;                // 0..255
    sv[t] = sc[blk * 512 + t];             si[t] = t;
    sv[t + 256] = sc[blk * 512 + t + 256]; si[t + 256] = t + 256;
    __syncthreads();
    for (int k2 = 2; k2 <= 512; k2 <<= 1) {
        for (int j = k2 >> 1; j > 0; j >>= 1) {
            for (int i = t; i < 512; i += 256) {
                int l = i ^ j;
                if (l > i) {
                    bool desc = ((i & k2) == 0);
                    float a = sv[i], bb2 = sv[l];
                    bool sw = desc ? (a < bb2) : (a > bb2);
                    if (sw) {
                        sv[i] = bb2; sv[l] = a;
                        int tmp = si[i]; si[i] = si[l]; si[l] = tmp;
                    }
                }
            }
            __syncthreads();
        }
    }
    sel[blk * 256 + t] = si[t];
    nmap[blk * 512 + si[t]] = blk * 256 + t;
    nmap[blk * 512 + si[t + 256]] = -1;
}

// ---------------- final attention pool (fused alpha + weighted segment sum) ----------------
__global__ void k_cfin(const float* __restrict__ meansum, const float* __restrict__ Wg,
                       float* __restrict__ cf) {
    __shared__ float ms[128];
    int b = blockIdx.x; int c = threadIdx.x;
    ms[c] = meansum[b * 128 + c] * (1.0f / 256.0f);
    __syncthreads();
    float s = 0.f;
    for (int k = 0; k < 128; k++) s = fmaf(ms[k], Wg[k * 128 + c], s);
    cf[b * 128 + c] = tanhf(s);
}

__global__ __launch_bounds__(256) void k_attpool_fin(const float* __restrict__ H,
                                                     const float* __restrict__ cf,
                                                     float* __restrict__ g12) {
    __shared__ float gps[4][128];
    int seg = blockIdx.x;               // 0..127 = comm*64 + b
    int w = threadIdx.x >> 6, l = threadIdx.x & 63;
    const float2 cfl = *(const float2*)(cf + seg * 128 + 2 * l);
    float2 acc = {0.f, 0.f};
    int base = seg * 256 + w * 64;
    for (int it = 0; it < 64; it++) {
        const float2 h = *(const float2*)(H + (size_t)(base + it) * 128 + 2 * l);
        float s = h.x * cfl.x + h.y * cfl.y;
        for (int off = 32; off; off >>= 1) s += __shfl_xor(s, off);
        float al = 1.f / (1.f + expf(-s));
        acc.x += h.x * al; acc.y += h.y * al;
    }
    *(float2*)&gps[w][2 * l] = acc;
    __syncthreads();
    if (threadIdx.x < 128) {
        int c = threadIdx.x;
        float s = gps[0][c] + gps[1][c] + gps[2][c] + gps[3][c];
        int b = seg & 63, comm = seg >> 6;
        g12[b * 256 + comm * 128 + c] = s;
    }
}

// ---------------- MLP head ----------------
__global__ void k_mlp(const float* __restrict__ G,
                      const float* __restrict__ Wl1, const float* __restrict__ bl1,
                      const float* __restrict__ Wl2, const float* __restrict__ bl2,
                      const float* __restrict__ Wl3, const float* __restrict__ bl3,
                      float* __restrict__ out) {
    __shared__ float t1[128], t2[64];
    int b = blockIdx.x; int t = threadIdx.x;
    float s = bl1[t];
    for (int k = 0; k < 256; k++) s = fmaf(G[b * 256 + k], Wl1[k * 128 + t], s);
    t1[t] = fmaxf(s, 0.f);
    __syncthreads();
    if (t < 64) {
        float s2 = bl2[t];
        for (int k = 0; k < 128; k++) s2 = fmaf(t1[k], Wl2[k * 64 + t], s2);
        t2[t] = fmaxf(s2, 0.f);
    }
    __syncthreads();
    if (t < 2) {
        float s3 = bl3[t];
        for (int k = 0; k < 64; k++) s3 = fmaf(t2[k], Wl3[k * 2 + t], s3);
        out[b * 2 + t] = s3;
    }
}

// ---------------- launch ----------------
extern "C" void kernel_launch(void* const* d_in, const int* in_sizes, int n_in,
                              void* d_out, int out_size, void* d_ws, size_t ws_size,
                              hipStream_t stream) {
    const float* x       = (const float*)d_in[0];
    const int*   src_all = (const int*)d_in[1];
    const int*   dst_all = (const int*)d_in[2];
    const int*   src_c1  = (const int*)d_in[3];
    const int*   dst_c1  = (const int*)d_in[4];
    const int*   src_c2  = (const int*)d_in[5];
    const int*   dst_c2  = (const int*)d_in[6];
    const float* W1 = (const float*)d_in[7];   const float* b1 = (const float*)d_in[8];
    const float* W2 = (const float*)d_in[9];   const float* b2 = (const float*)d_in[10];
    const float* W3 = (const float*)d_in[11];  const float* b3 = (const float*)d_in[12];
    const float* Wg_att = (const float*)d_in[13];
    const float* Wal = (const float*)d_in[14]; const float* bal = (const float*)d_in[15];
    const float* Wf  = (const float*)d_in[16]; const float* bf  = (const float*)d_in[17];
    const float* Wg_fin = (const float*)d_in[18];
    const float* Wl1 = (const float*)d_in[19]; const float* bl1 = (const float*)d_in[20];
    const float* Wl2 = (const float*)d_in[21]; const float* bl2 = (const float*)d_in[22];
    const float* Wl3 = (const float*)d_in[23]; const float* bl3 = (const float*)d_in[24];
    float* out = (float*)d_out;

    // ---- workspace layout (floats) ----
    float* f = (float*)d_ws;
    size_t o = 0;
    float* XC   = f + o; o += (size_t)NN * 384;
    float* SCR  = f + o; o += (size_t)NN * 128;     // xw*dis; later XWP (NP2 x 128)
    float* H    = f + o; o += (size_t)NP2 * 128;    // pooled conv out; earlier aliased as MPART
    int* ROWSTART = (int*)(f + o); o += 65552;
    int* CSRC     = (int*)(f + o); o += EALL;
    int* CNTP     = (int*)(f + o); o += NP2;
    float* DIS    = f + o; o += NN;
    float* GPP    = f + o; o += 512 * 384;          // GP partial slots (deterministic)
    float* MEANF  = f + o; o += 128 * 128;          // atomic (continuous path)
    float* C12    = f + o; o += 128 * 384;
    float* PV     = f + o; o += 64 * 768;
    float* PNORM  = f + o; o += 128;
    float* SC     = f + o; o += 65536;
    int* SEL      = (int*)(f + o); o += NP2;
    int* NMAP     = (int*)(f + o); o += 65536;
    float* DISP   = f + o; o += NP2;
    float* CFIN   = f + o; o += 128 * 128;
    float* G12    = f + o; o += 64 * 256;
    unsigned short* WBH = (unsigned short*)(f + o); o += 49152;   // 98304 bf16 (W1,W2,W3,Wf)
    unsigned short* WBL = (unsigned short*)(f + o); o += 49152;
    size_t needed_bytes = o * sizeof(float);
    if (ws_size < needed_bytes) return;

    float* MPART = H;                   // 128*64*384 = 3.1M floats <= H region — H written later
    float* XWP   = SCR;                 // pooled GEMM output (NP2 x 128), reuses SCR

    // zero the remaining atomic accumulator (MEANF only)
    hipMemsetAsync(MEANF, 0, 128 * 128 * sizeof(float), stream);

    // ---- W prep (transpose + bf16 hi/lo for all 4 matrices) ----
    k_prep_w<<<384, 256, 0, stream>>>(W1, W2, W3, Wf, WBH, WBL);

    // ---- full-graph CSR + degrees ----
    k_build_csr<<<128, 256, 0, stream>>>(src_all, dst_all, ROWSTART, CSRC, DIS);

    // ---- 3 GCN layers (MFMA bf16x3 GEMM — deterministic; GP/MSUM reductions fixed-order) ----
    k_gemm_mfma<128><<<NN / 128, 256, 0, stream>>>(x, 128, WBH, WBL, DIS, SCR);
    k_aggregate4<<<NN / 8, 256, 0, stream>>>(SCR, DIS, ROWSTART, CSRC, b1, XC, 0, MPART);
    k_gemm_mfma<128><<<NN / 128, 256, 0, stream>>>(XC + 0, 384, WBH + 16384, WBL + 16384, DIS, SCR);
    k_aggregate4<<<NN / 8, 256, 0, stream>>>(SCR, DIS, ROWSTART, CSRC, b2, XC, 128, MPART);
    k_gemm_mfma<128><<<NN / 128, 256, 0, stream>>>(XC + 128, 384, WBH + 32768, WBL + 32768, DIS, SCR);
    k_aggregate4<<<NN / 8, 256, 0, stream>>>(SCR, DIS, ROWSTART, CSRC, b3, XC, 256, MPART);

    // ---- attention pool over communities (deterministic reductions) ----
    k_c12<<<128, 384, 0, stream>>>(MPART, Wg_att, C12);
    k_attpool1<<<512, 256, 0, stream>>>(XC, C12, GPP);
    k_pv<<<64, 768, 0, stream>>>(GPP, Wal, bal, PV, PNORM);

    // ---- scores + top-K ----
    k_score<<<65536 / 4, 256, 0, stream>>>(XC, PV, PNORM, SC);
    k_topk<<<128, 256, 0, stream>>>(SC, SEL, NMAP);

    // ---- pooled graph build ----
    k_build_csr_pooled<<<128, 256, 0, stream>>>(src_c1, dst_c1, src_c2, dst_c2,
                                                NMAP, ROWSTART, CNTP, CSRC, DISP);

    // ---- pooled GCN (MFMA bf16x3 gathered GEMM) ----
    k_gemm_gather_mfma<<<NP2 / 128, 256, 0, stream>>>(XC, SEL, SC, DISP,
                                                      WBH + 49152, WBL + 49152, XWP);
    k_aggregate_pooled<<<NP2 / 8, 256, 0, stream>>>(XWP, DISP, ROWSTART, CNTP, CSRC,
                                                    bf, H, MEANF);

    // ---- final attention pool (fused) ----
    k_cfin<<<128, 128, 0, stream>>>(MEANF, Wg_fin, CFIN);
    k_attpool_fin<<<128, 256, 0, stream>>>(H, CFIN, G12);

    // ---- MLP head ----
    k_mlp<<<64, 128, 0, stream>>>(G12, Wl1, bl1, Wl2, bl2, Wl3, bl3, out);
}